// Round 6
// baseline (1494.283 us; speedup 1.0000x reference)
//
#include <hip/hip_runtime.h>
#include <hip/hip_bf16.h>
#include <math.h>

constexpr int kN   = 20000;
constexpr int kE   = 256000;
constexpr int kESM = 1280;
constexpr int kHC  = 1024;

typedef unsigned int  u32;
typedef unsigned short ushort_t;
typedef __bf16 bf16x8 __attribute__((ext_vector_type(8)));
typedef float  f32x4  __attribute__((ext_vector_type(4)));
typedef unsigned short u16x8 __attribute__((ext_vector_type(8)));
typedef unsigned short u16x4 __attribute__((ext_vector_type(4)));
typedef __attribute__((address_space(1))) const u32 gu32;
typedef __attribute__((address_space(3))) u32 lu32;

static __device__ __forceinline__ unsigned short f2bf_rne(float f) {
    u32 u = __float_as_uint(f);
    u32 r = (u + 0x7FFFu + ((u >> 16) & 1u)) >> 16;
    return (unsigned short)r;
}
static __device__ __forceinline__ float bf2f(unsigned short h) {
    return __uint_as_float(((u32)h) << 16);
}

// ---------------------------------------------------------------------------
// K1: degree + weighted-degree via atomics
// ---------------------------------------------------------------------------
__global__ __launch_bounds__(256) void deg_kernel(
    const int* __restrict__ dst, const float* __restrict__ ew,
    int* __restrict__ deg, float* __restrict__ wsum)
{
    int e = blockIdx.x * 256 + threadIdx.x;
    if (e < kE) {
        int d = dst[e];
        atomicAdd(&deg[d], 1);
        atomicAdd(&wsum[d], ew[e]);
    }
}

// ---------------------------------------------------------------------------
// K2: single-block exclusive scan of deg -> offsets; loop_attr = wsum/max(deg,1)
// ---------------------------------------------------------------------------
__global__ __launch_bounds__(256) void scan_kernel(
    const int* __restrict__ deg, float* __restrict__ loopat,
    int* __restrict__ offsets)
{
    __shared__ int s[256];
    int tid = threadIdx.x;
    int base = 0;
    if (tid == 0) offsets[0] = 0;
    for (int t0 = 0; t0 < kN; t0 += 256) {
        int i = t0 + tid;
        int d = (i < kN) ? deg[i] : 0;
        if (i < kN) {
            float w = loopat[i];
            loopat[i] = w / fmaxf((float)d, 1.0f);
        }
        s[tid] = d;
        int v = d;
        for (int off = 1; off < 256; off <<= 1) {
            __syncthreads();
            int add = (tid >= off) ? s[tid - off] : 0;
            __syncthreads();
            v += add;
            s[tid] = v;
        }
        __syncthreads();
        if (i < kN) offsets[i + 1] = base + v;
        base += s[255];
        __syncthreads();
    }
}

// ---------------------------------------------------------------------------
// K3: scatter edges into dst-sorted order
// ---------------------------------------------------------------------------
__global__ __launch_bounds__(256) void sort_kernel(
    const int* __restrict__ src, const int* __restrict__ dst,
    const float* __restrict__ ew, const int* __restrict__ offsets,
    int* __restrict__ cnt, int* __restrict__ ssrc, float* __restrict__ sew)
{
    int e = blockIdx.x * 256 + threadIdx.x;
    if (e < kE) {
        int d = dst[e];
        int p = offsets[d] + atomicAdd(&cnt[d], 1);
        ssrc[p] = src[e];
        sew[p]  = ew[e];
    }
}

// ===========================================================================
// FAST PATH: bf16x3 split MFMA GEMM with pre-packed operands.
// Packed tile layout per (mb/nb, kb): [hl(2)][g(4)][rc(128)][8] bf16 = 16 KB.
// Fragment read: lane l -> rc = base + (l&15), g = l>>4 -> one ds_read_b128.
// ===========================================================================

// pack A (fp32 [M][K], zero-pad rows >= M).  grid (NKB, MB), 512 thr.
__global__ __launch_bounds__(512) void pack_a_kernel(
    const float* __restrict__ A, int M, int K,
    int NKB, ushort_t* __restrict__ dst)
{
    const int kb = blockIdx.x, mb = blockIdx.y;
    const int tid = threadIdx.x;
    const int g = tid >> 7, r = tid & 127;
    const int row = mb * 128 + r;

    u16x8 hi, lo;
    if (row < M) {
        const float* src = A + (size_t)row * K + kb * 32 + g * 8;
        float4 v0 = *(const float4*)src;
        float4 v1 = *(const float4*)(src + 4);
        float vals[8] = {v0.x, v0.y, v0.z, v0.w, v1.x, v1.y, v1.z, v1.w};
#pragma unroll
        for (int j = 0; j < 8; ++j) {
            unsigned short h = f2bf_rne(vals[j]);
            hi[j] = h;
            lo[j] = f2bf_rne(vals[j] - bf2f(h));
        }
    } else {
#pragma unroll
        for (int j = 0; j < 8; ++j) { hi[j] = 0; lo[j] = 0; }
    }
    ushort_t* tb = dst + ((size_t)mb * NKB + kb) * 8192;
    *(u16x8*)&tb[0    + g * 1024 + r * 8] = hi;
    *(u16x8*)&tb[4096 + g * 1024 + r * 8] = lo;
}

// pack A2 = [agg(fp32) | h(bf16)] logical [M][2048].  grid (64, MB), 512 thr.
// For kb >= 32 (the h half) A-lo is exactly zero -> NOT written; gemm_mfma
// loads that plane (uniform vmcnt counting) but never multiplies it.
__global__ __launch_bounds__(512) void pack_a2_kernel(
    const float* __restrict__ agg, const ushort_t* __restrict__ hb,
    int M, ushort_t* __restrict__ dst)
{
    const int kb = blockIdx.x, mb = blockIdx.y;   // kb in [0,64)
    const int tid = threadIdx.x;
    const int g = tid >> 7, r = tid & 127;
    const int row = mb * 128 + r;
    ushort_t* tb = dst + ((size_t)mb * 64 + kb) * 8192;

    if (kb < 32) {
        u16x8 hi, lo;
        if (row < M) {
            const float* src = agg + (size_t)row * 1024 + kb * 32 + g * 8;
            float4 v0 = *(const float4*)src;
            float4 v1 = *(const float4*)(src + 4);
            float vals[8] = {v0.x, v0.y, v0.z, v0.w, v1.x, v1.y, v1.z, v1.w};
#pragma unroll
            for (int j = 0; j < 8; ++j) {
                unsigned short h = f2bf_rne(vals[j]);
                hi[j] = h;
                lo[j] = f2bf_rne(vals[j] - bf2f(h));
            }
        } else {
#pragma unroll
            for (int j = 0; j < 8; ++j) { hi[j] = 0; lo[j] = 0; }
        }
        *(u16x8*)&tb[0    + g * 1024 + r * 8] = hi;
        *(u16x8*)&tb[4096 + g * 1024 + r * 8] = lo;
    } else {
        u16x8 hi;
        if (row < M) {
            hi = *(const u16x8*)&hb[(size_t)row * 1024 + (kb - 32) * 32 + g * 8];
        } else {
#pragma unroll
            for (int j = 0; j < 8; ++j) hi[j] = 0;
        }
        *(u16x8*)&tb[0 + g * 1024 + r * 8] = hi;   // lo plane left unwritten (loaded, never used)
    }
}

// pack B. mode 0 (col-split): B(k,n) = n<split ? B1[k][n] : B2[k][n-split]
//         mode 1 (row-split): B(k,n) = k<split ? B1[k][n] : B2[(k-split)][n]
// grid (NKB, N/128), 512 thr.
__global__ __launch_bounds__(512) void pack_b_kernel(
    const float* __restrict__ B1, const float* __restrict__ B2,
    int N, int split, int mode, ushort_t* __restrict__ dst)
{
    const int kb = blockIdx.x, nb = blockIdx.y;
    const int NKB = gridDim.x;
    const int tid = threadIdx.x;
    const int g = tid >> 7, c = tid & 127;
    const int n = nb * 128 + c;

    u16x8 hi, lo;
#pragma unroll
    for (int j = 0; j < 8; ++j) {
        int k = kb * 32 + g * 8 + j;
        float v;
        if (mode == 0) {
            v = (n < split) ? B1[(size_t)k * split + n]
                            : B2[(size_t)k * (N - split) + (n - split)];
        } else {
            v = (k < split) ? B1[(size_t)k * N + n]
                            : B2[(size_t)(k - split) * N + n];
        }
        unsigned short h = f2bf_rne(v);
        hi[j] = h;
        lo[j] = f2bf_rne(v - bf2f(h));
    }
    ushort_t* tb = dst + ((size_t)nb * NKB + kb) * 8192;
    *(u16x8*)&tb[0    + g * 1024 + c * 8] = hi;
    *(u16x8*)&tb[4096 + g * 1024 + c * 8] = lo;
}

// bf16x3 MFMA GEMM: C = epi(Ahi*Bhi + Ahi*Blo + Alo*Bhi).
// 128x128 tile, BK=32, 4 waves (2x2), 4x4 16x16x32 frags per wave.
// kb >= nkb_full: A-lo known-zero, 2 products (lo plane still loaded, unused).
// Double-buffered LDS (64KB) + depth-2 prefetch + counted vmcnt(8) (T3/T4):
//   ds_read buf[p] -> lgkmcnt(0)+barrier -> stage tile kt+2 into buf[p]
//   -> MFMA (loads fly underneath) -> vmcnt(8)+barrier (tile kt+1 landed).
// XCD-aware bijective block swizzle (m204) for A-panel L2 locality.
__global__ __launch_bounds__(256) void gemm_mfma(
    const ushort_t* __restrict__ Ap, const ushort_t* __restrict__ Bp,
    const float* __restrict__ bias, int biasN,
    const float* __restrict__ resid, float* __restrict__ C,
    int M, int N, int NKB, int nkb_full, int do_relu)
{
    __shared__ ushort_t sb[32768];   // 64KB: 2 buffers x (A 16KB + B 16KB)
    const int tid  = threadIdx.x;
    const int wid  = tid >> 6;
    const int lane = tid & 63;
    const int l15 = lane & 15, l4 = lane >> 4;

    // bijective XCD swizzle: same-XCD blocks get consecutive (mb,nb)
    const int nwg = gridDim.x * gridDim.y;
    const int lin = blockIdx.y * gridDim.x + blockIdx.x;
    const int q = nwg >> 3, r = nwg & 7;
    const int xcd = lin & 7, pos = lin >> 3;
    const int swz = (xcd < r ? xcd * (q + 1) : r * (q + 1) + (xcd - r) * q) + pos;
    const int mb = swz / gridDim.x, nb = swz % gridDim.x;
    const int wr = wid >> 1, wc = wid & 1;

    f32x4 acc[4][4];
#pragma unroll
    for (int i = 0; i < 4; ++i)
#pragma unroll
        for (int j = 0; j < 4; ++j) acc[i][j] = (f32x4){0.f, 0.f, 0.f, 0.f};

    const char* at = (const char*)(Ap + (size_t)mb * NKB * 8192);
    const char* bt = (const char*)(Bp + (size_t)nb * NKB * 8192);

    // stage tile kb into buffer buf (8 x global_load_lds dwordx4 per thread)
    auto stage = [&](int kb, int buf) {
        const char* atk = at + (size_t)kb * 16384;
        const char* btk = bt + (size_t)kb * 16384;
        const int sbase = buf << 14;   // buf * 16384 ushorts = 32KB
#pragma unroll
        for (int c = 0; c < 4; ++c) {
            __builtin_amdgcn_global_load_lds(
                (gu32*)(atk + c * 4096 + tid * 16),
                (lu32*)&sb[sbase + c * 2048 + wid * 512], 16, 0, 0);
            __builtin_amdgcn_global_load_lds(
                (gu32*)(btk + c * 4096 + tid * 16),
                (lu32*)&sb[sbase + 8192 + c * 2048 + wid * 512], 16, 0, 0);
        }
    };

    // prologue: stage tiles 0 and 1; wait only tile 0 (vmcnt(8))
    stage(0, 0);
    stage(1, 1);
    asm volatile("s_waitcnt vmcnt(8)" ::: "memory");
    __builtin_amdgcn_sched_barrier(0);
    __builtin_amdgcn_s_barrier();
    __builtin_amdgcn_sched_barrier(0);

    for (int kt = 0; kt < NKB; ++kt) {
        const int p = kt & 1;
        const int sbase = p << 14;
        const bool full = (kt < nkb_full);
        const bool pre  = (kt + 2 < NKB);

        bf16x8 af0[4], af1[4], bv[2][4];
#pragma unroll
        for (int m = 0; m < 4; ++m)
            af0[m] = *(const bf16x8*)&sb[sbase + l4 * 1024 + (wr * 64 + m * 16 + l15) * 8];
        if (full) {
#pragma unroll
            for (int m = 0; m < 4; ++m)
                af1[m] = *(const bf16x8*)&sb[sbase + 4096 + l4 * 1024 + (wr * 64 + m * 16 + l15) * 8];
        }
#pragma unroll
        for (int hl = 0; hl < 2; ++hl)
#pragma unroll
            for (int n = 0; n < 4; ++n)
                bv[hl][n] = *(const bf16x8*)&sb[sbase + 8192 + hl * 4096 + l4 * 1024 + (wc * 64 + n * 16 + l15) * 8];

        // all waves done reading buf[p] before anyone overwrites it
        asm volatile("s_waitcnt lgkmcnt(0)" ::: "memory");
        __builtin_amdgcn_sched_barrier(0);
        __builtin_amdgcn_s_barrier();
        __builtin_amdgcn_sched_barrier(0);

        if (pre) stage(kt + 2, p);   // overwrite just-read buffer, depth-2 ahead

#pragma unroll
        for (int m = 0; m < 4; ++m)
#pragma unroll
            for (int n = 0; n < 4; ++n) {
                acc[m][n] = __builtin_amdgcn_mfma_f32_16x16x32_bf16(af0[m], bv[0][n], acc[m][n], 0, 0, 0);
                acc[m][n] = __builtin_amdgcn_mfma_f32_16x16x32_bf16(af0[m], bv[1][n], acc[m][n], 0, 0, 0);
            }
        if (full) {
#pragma unroll
            for (int m = 0; m < 4; ++m)
#pragma unroll
                for (int n = 0; n < 4; ++n)
                    acc[m][n] = __builtin_amdgcn_mfma_f32_16x16x32_bf16(af1[m], bv[0][n], acc[m][n], 0, 0, 0);
        }

        // wait tile kt+1 landed (8 newest = tile kt+2 may stay in flight)
        if (pre) { asm volatile("s_waitcnt vmcnt(8)" ::: "memory"); }
        else     { asm volatile("s_waitcnt vmcnt(0)" ::: "memory"); }
        __builtin_amdgcn_sched_barrier(0);
        __builtin_amdgcn_s_barrier();
        __builtin_amdgcn_sched_barrier(0);
    }

    const int row_w = mb * 128 + wr * 64;
    const int col_w = nb * 128 + wc * 64;
#pragma unroll
    for (int m = 0; m < 4; ++m) {
#pragma unroll
        for (int n = 0; n < 4; ++n) {
            const int col = col_w + n * 16 + l15;
#pragma unroll
            for (int j = 0; j < 4; ++j) {
                const int row = row_w + m * 16 + l4 * 4 + j;
                if (row < M) {
                    float v = acc[m][n][j];
                    if (bias && col < biasN) v += bias[col];
                    if (do_relu) v = fmaxf(v, 0.f);
                    if (resid) v += resid[(size_t)row * N + col];
                    C[(size_t)row * N + col] = v;
                }
            }
        }
    }
}

// fused GAT (fast path): xlr fp32 [N][2048] (xl cols 0..1023, xr 1024..2047),
// h out bf16 [N][1024].
__global__ __launch_bounds__(256) void gat2_kernel(
    const float* __restrict__ xlr, const int* __restrict__ ssrc,
    const float* __restrict__ sew, const int* __restrict__ offsets,
    const float* __restrict__ loopat, const float* __restrict__ We,
    const float* __restrict__ att, const float* __restrict__ bgat,
    ushort_t* __restrict__ hout)
{
    const int n = blockIdx.x;
    const int base = threadIdx.x * 4;

    const float4 xr4 = *(const float4*)&xlr[(size_t)n * 2048 + 1024 + base];
    const float4 We4 = *(const float4*)&We[base];
    const float4 at4 = *(const float4*)&att[base];

    float M = -INFINITY, D = 0.f;
    float4 acc = make_float4(0.f, 0.f, 0.f, 0.f);

    const int beg = offsets[n], end = offsets[n + 1];
    for (int e = beg; e <= end; ++e) {
        int s; float w;
        if (e < end) { s = ssrc[e]; w = sew[e]; }
        else         { s = n;       w = loopat[n]; }

        const float4 xls = *(const float4*)&xlr[(size_t)s * 2048 + base];
        float m0 = xls.x + xr4.x + w * We4.x;
        float m1 = xls.y + xr4.y + w * We4.y;
        float m2 = xls.z + xr4.z + w * We4.z;
        float m3 = xls.w + xr4.w + w * We4.w;
        m0 = (m0 >= 0.f) ? m0 : 0.2f * m0;
        m1 = (m1 >= 0.f) ? m1 : 0.2f * m1;
        m2 = (m2 >= 0.f) ? m2 : 0.2f * m2;
        m3 = (m3 >= 0.f) ? m3 : 0.2f * m3;
        float p = m0 * at4.x + m1 * at4.y + m2 * at4.z + m3 * at4.w;
#pragma unroll
        for (int o = 32; o >= 1; o >>= 1) p += __shfl_xor(p, o, 64);

        float newM  = fmaxf(M, p);
        float scale = __expf(M - newM);
        float wexp  = __expf(p - newM);
        D     = D * scale + wexp;
        acc.x = acc.x * scale + wexp * xls.x;
        acc.y = acc.y * scale + wexp * xls.y;
        acc.z = acc.z * scale + wexp * xls.z;
        acc.w = acc.w * scale + wexp * xls.w;
        M = newM;
    }

    const float inv = 1.0f / (D + 1e-16f);
    float g0 = acc.x * inv + bgat[base + 0];
    float g1 = acc.y * inv + bgat[base + 1];
    float g2 = acc.z * inv + bgat[base + 2];
    float g3 = acc.w * inv + bgat[base + 3];
    u16x4 hv;
    hv[0] = f2bf_rne((g0 > 0.f) ? g0 : expm1f(g0));
    hv[1] = f2bf_rne((g1 > 0.f) ? g1 : expm1f(g1));
    hv[2] = f2bf_rne((g2 > 0.f) ? g2 : expm1f(g2));
    hv[3] = f2bf_rne((g3 > 0.f) ? g3 : expm1f(g3));
    *(u16x4*)&hout[(size_t)n * 1024 + base] = hv;
}

// agg (fast path): mean of bf16 h[src] rows -> fp32 agg
__global__ __launch_bounds__(256) void agg2_kernel(
    const ushort_t* __restrict__ hb, const int* __restrict__ ssrc,
    const int* __restrict__ offsets, float* __restrict__ aggout)
{
    const int n = blockIdx.x;
    const int base = threadIdx.x * 4;
    float4 a = make_float4(0.f, 0.f, 0.f, 0.f);
    const int beg = offsets[n], end = offsets[n + 1];
    for (int e = beg; e < end; ++e) {
        const u16x4 hv = *(const u16x4*)&hb[(size_t)ssrc[e] * 1024 + base];
        a.x += bf2f(hv[0]); a.y += bf2f(hv[1]);
        a.z += bf2f(hv[2]); a.w += bf2f(hv[3]);
    }
    const float inv = 1.0f / fmaxf((float)(end - beg), 1.0f);
    a.x *= inv; a.y *= inv; a.z *= inv; a.w *= inv;
    *(float4*)&aggout[(size_t)n * 1024 + base] = a;
}

// ---------------------------------------------------------------------------
// LayerNorm over last dim (1280), in-place. 320 threads x float4 per row.
// ---------------------------------------------------------------------------
__global__ __launch_bounds__(320) void ln_kernel(
    float* __restrict__ z, const float* __restrict__ gamma,
    const float* __restrict__ beta)
{
    const int r = blockIdx.x;
    const int t = threadIdx.x;
    const int wave = t >> 6, lane = t & 63;
    __shared__ float red[5];

    float4 v = *(const float4*)&z[(size_t)r * kESM + t * 4];
    float s = v.x + v.y + v.z + v.w;
#pragma unroll
    for (int o = 32; o >= 1; o >>= 1) s += __shfl_xor(s, o, 64);
    if (lane == 0) red[wave] = s;
    __syncthreads();
    s = red[0] + red[1] + red[2] + red[3] + red[4];
    const float mu = s * (1.0f / (float)kESM);

    float dx = v.x - mu, dy = v.y - mu, dz = v.z - mu, dw = v.w - mu;
    float q = dx * dx + dy * dy + dz * dz + dw * dw;
#pragma unroll
    for (int o = 32; o >= 1; o >>= 1) q += __shfl_xor(q, o, 64);
    __syncthreads();
    if (lane == 0) red[wave] = q;
    __syncthreads();
    q = red[0] + red[1] + red[2] + red[3] + red[4];
    const float rstd = rsqrtf(q * (1.0f / (float)kESM) + 1e-5f);

    const float4 g4 = *(const float4*)&gamma[t * 4];
    const float4 b4 = *(const float4*)&beta[t * 4];
    float4 o;
    o.x = dx * rstd * g4.x + b4.x;
    o.y = dy * rstd * g4.y + b4.y;
    o.z = dz * rstd * g4.z + b4.z;
    o.w = dw * rstd * g4.w + b4.w;
    *(float4*)&z[(size_t)r * kESM + t * 4] = o;
}

// ===========================================================================
// FALLBACK PATH (round-2, known-pass): fp32 vector GEMM + fp32 gat/agg
// ===========================================================================
#define BM 128
#define BN 128
#define BK 16

__global__ __launch_bounds__(256) void gemm_kernel(
    const float* __restrict__ A,  const float* __restrict__ B,
    const float* __restrict__ A2, const float* __restrict__ B2,
    const float* __restrict__ bias, const float* __restrict__ resid,
    float* __restrict__ C, int M, int N, int K, int do_relu)
{
    __shared__ float As[BK][BM];
    __shared__ float Bs[BK][BN];

    const int tid = threadIdx.x;
    const int bm = blockIdx.y, bn = blockIdx.x;
    const int row0 = bm * BM, col0 = bn * BN;
    const int tx = tid & 15, ty = tid >> 4;

    float acc[8][8];
#pragma unroll
    for (int i = 0; i < 8; ++i)
#pragma unroll
        for (int j = 0; j < 8; ++j) acc[i][j] = 0.0f;

    const int arow  = tid >> 1;
    const int akoff = (tid & 1) * 8;
    const int bkr   = tid >> 4;
    const int bcol  = (tid & 15) * 8;

    for (int pair = 0; pair < 2; ++pair) {
        const float* Ap = pair ? A2 : A;
        const float* Bp = pair ? B2 : B;
        if (!Ap) break;
        for (int k0 = 0; k0 < K; k0 += BK) {
            float4 a0 = make_float4(0.f, 0.f, 0.f, 0.f);
            float4 a1 = a0;
            int gr = row0 + arow;
            if (gr < M) {
                const float* aptr = Ap + (size_t)gr * K + k0 + akoff;
                a0 = *(const float4*)aptr;
                a1 = *(const float4*)(aptr + 4);
            }
            const float* bptr = Bp + (size_t)(k0 + bkr) * N + col0 + bcol;
            float4 b0 = *(const float4*)bptr;
            float4 b1 = *(const float4*)(bptr + 4);

            __syncthreads();
            As[akoff + 0][arow] = a0.x;
            As[akoff + 1][arow] = a0.y;
            As[akoff + 2][arow] = a0.z;
            As[akoff + 3][arow] = a0.w;
            As[akoff + 4][arow] = a1.x;
            As[akoff + 5][arow] = a1.y;
            As[akoff + 6][arow] = a1.z;
            As[akoff + 7][arow] = a1.w;
            *(float4*)&Bs[bkr][bcol]     = b0;
            *(float4*)&Bs[bkr][bcol + 4] = b1;
            __syncthreads();

#pragma unroll
            for (int kk = 0; kk < BK; ++kk) {
                float4 a0r = *(const float4*)&As[kk][ty * 8];
                float4 a1r = *(const float4*)&As[kk][ty * 8 + 4];
                float4 b0r = *(const float4*)&Bs[kk][tx * 4];
                float4 b1r = *(const float4*)&Bs[kk][64 + tx * 4];
                float ar[8] = {a0r.x, a0r.y, a0r.z, a0r.w, a1r.x, a1r.y, a1r.z, a1r.w};
                float br[8] = {b0r.x, b0r.y, b0r.z, b0r.w, b1r.x, b1r.y, b1r.z, b1r.w};
#pragma unroll
                for (int i = 0; i < 8; ++i)
#pragma unroll
                    for (int j = 0; j < 8; ++j)
                        acc[i][j] = fmaf(ar[i], br[j], acc[i][j]);
            }
        }
    }

#pragma unroll
    for (int i = 0; i < 8; ++i) {
        int gr = row0 + ty * 8 + i;
        if (gr >= M) break;
#pragma unroll
        for (int half = 0; half < 2; ++half) {
            int gc = col0 + half * 64 + tx * 4;
            float4 out;
            float* o = &out.x;
            const float* rrow = resid ? (resid + (size_t)gr * N + gc) : nullptr;
#pragma unroll
            for (int j = 0; j < 4; ++j) {
                float v = acc[i][half * 4 + j];
                if (bias) v += bias[gc + j];
                if (do_relu) v = fmaxf(v, 0.0f);
                if (rrow) v += rrow[j];
                o[j] = v;
            }
            *(float4*)&C[(size_t)gr * N + gc] = out;
        }
    }
}

__global__ __launch_bounds__(256) void gat_kernel(
    const float* __restrict__ xl, const float* __restrict__ xr,
    const int* __restrict__ ssrc, const float* __restrict__ sew,
    const int* __restrict__ offsets, const float* __restrict__ loopat,
    const float* __restrict__ We, const float* __restrict__ att,
    const float* __restrict__ bgat, float* __restrict__ hout)
{
    const int n = blockIdx.x;
    const int base = threadIdx.x * 4;

    const float4 xr4 = *(const float4*)&xr[(size_t)n * kHC + base];
    const float4 We4 = *(const float4*)&We[base];
    const float4 at4 = *(const float4*)&att[base];

    float M = -INFINITY, D = 0.f;
    float4 acc = make_float4(0.f, 0.f, 0.f, 0.f);

    const int beg = offsets[n], end = offsets[n + 1];
    for (int e = beg; e <= end; ++e) {
        int s; float w;
        if (e < end) { s = ssrc[e]; w = sew[e]; }
        else         { s = n;       w = loopat[n]; }

        const float4 xls = *(const float4*)&xl[(size_t)s * kHC + base];
        float m0 = xls.x + xr4.x + w * We4.x;
        float m1 = xls.y + xr4.y + w * We4.y;
        float m2 = xls.z + xr4.z + w * We4.z;
        float m3 = xls.w + xr4.w + w * We4.w;
        m0 = (m0 >= 0.f) ? m0 : 0.2f * m0;
        m1 = (m1 >= 0.f) ? m1 : 0.2f * m1;
        m2 = (m2 >= 0.f) ? m2 : 0.2f * m2;
        m3 = (m3 >= 0.f) ? m3 : 0.2f * m3;
        float p = m0 * at4.x + m1 * at4.y + m2 * at4.z + m3 * at4.w;
#pragma unroll
        for (int o = 32; o >= 1; o >>= 1) p += __shfl_xor(p, o, 64);

        float newM  = fmaxf(M, p);
        float scale = __expf(M - newM);
        float wexp  = __expf(p - newM);
        D     = D * scale + wexp;
        acc.x = acc.x * scale + wexp * xls.x;
        acc.y = acc.y * scale + wexp * xls.y;
        acc.z = acc.z * scale + wexp * xls.z;
        acc.w = acc.w * scale + wexp * xls.w;
        M = newM;
    }

    const float inv = 1.0f / (D + 1e-16f);
    float g0 = acc.x * inv + bgat[base + 0];
    float g1 = acc.y * inv + bgat[base + 1];
    float g2 = acc.z * inv + bgat[base + 2];
    float g3 = acc.w * inv + bgat[base + 3];
    float4 hv;
    hv.x = (g0 > 0.f) ? g0 : expm1f(g0);
    hv.y = (g1 > 0.f) ? g1 : expm1f(g1);
    hv.z = (g2 > 0.f) ? g2 : expm1f(g2);
    hv.w = (g3 > 0.f) ? g3 : expm1f(g3);
    *(float4*)&hout[(size_t)n * kHC + base] = hv;
}

__global__ __launch_bounds__(256) void agg_kernel(
    const float* __restrict__ h, const int* __restrict__ ssrc,
    const int* __restrict__ offsets, float* __restrict__ aggout)
{
    const int n = blockIdx.x;
    const int base = threadIdx.x * 4;
    float4 a = make_float4(0.f, 0.f, 0.f, 0.f);
    const int beg = offsets[n], end = offsets[n + 1];
    for (int e = beg; e < end; ++e) {
        const float4 hv = *(const float4*)&h[(size_t)ssrc[e] * kHC + base];
        a.x += hv.x; a.y += hv.y; a.z += hv.z; a.w += hv.w;
    }
    const float inv = 1.0f / fmaxf((float)(end - beg), 1.0f);
    a.x *= inv; a.y *= inv; a.z *= inv; a.w *= inv;
    *(float4*)&aggout[(size_t)n * kHC + base] = a;
}

// ---------------------------------------------------------------------------
extern "C" void kernel_launch(void* const* d_in, const int* in_sizes, int n_in,
                              void* d_out, int out_size, void* d_ws, size_t ws_size,
                              hipStream_t stream)
{
    const float* x     = (const float*)d_in[0];
    const int*   ei    = (const int*)  d_in[1];
    const float* ew    = (const float*)d_in[2];
    const float* Wl    = (const float*)d_in[3];
    const float* bl    = (const float*)d_in[4];
    const float* Wr    = (const float*)d_in[5];
    const float* We    = (const float*)d_in[6];
    const float* att   = (const float*)d_in[7];
    const float* bgat  = (const float*)d_in[8];
    const float* Wsl   = (const float*)d_in[9];
    const float* bsl   = (const float*)d_in[10];
    const float* Wsr   = (const float*)d_in[11];
    const float* gamma = (const float*)d_in[12];
    const float* beta  = (const float*)d_in[13];
    const int* src = ei;
    const int* dst = ei + kE;
    char* ws = (char*)d_ws;

    // fast-path layout (bytes)
    const size_t SZ_XPACK = (size_t)157 * 40 * 16384;        // 102,891,520
    const size_t SZ_XLR   = (size_t)kN * 2048 * 4;           // 163,840,000
    const size_t SZ_HBUF  = (size_t)kN * 1024 * 2;           //  40,960,000
    const size_t SZ_B1    = (size_t)16 * 40 * 16384;         //  10,485,760
    const size_t SZ_B2    = (size_t)10 * 64 * 16384;         //  10,485,760
    const size_t OFF_XLR  = SZ_XPACK;
    const size_t OFF_HBUF = OFF_XLR + SZ_XLR;
    const size_t OFF_B1   = OFF_HBUF + SZ_HBUF;
    const size_t OFF_B2   = OFF_B1 + SZ_B1;
    size_t off = OFF_B2 + SZ_B2;
    auto salloc = [&](size_t bytes) -> void* {
        void* p = ws + off;
        off = (off + bytes + 255) & ~(size_t)255;
        return p;
    };
    int*   deg    = (int*)  salloc((size_t)kN * 4);
    int*   cnt    = (int*)  salloc((size_t)kN * 4);
    int*   offs   = (int*)  salloc((size_t)(kN + 1) * 4);
    float* loopat = (float*)salloc((size_t)kN * 4);
    int*   ssrc   = (int*)  salloc((size_t)kE * 4);
    float* sew    = (float*)salloc((size_t)kE * 4);
    const size_t FAST_TOTAL = off;

    if (ws_size >= FAST_TOTAL) {
        // ------------------ FAST PATH ------------------
        ushort_t* xpack = (ushort_t*)(ws);
        float*    xlr   = (float*)   (ws + OFF_XLR);
        ushort_t* hbuf  = (ushort_t*)(ws + OFF_HBUF);
        ushort_t* b1p   = (ushort_t*)(ws + OFF_B1);
        ushort_t* b2p   = (ushort_t*)(ws + OFF_B2);
        // aliases (lifetimes verified): agg over tail of dead xlr; apack over dead xpack+xlr head
        float*    aggb  = (float*)   (ws + OFF_HBUF - (size_t)kN * 1024 * 4);
        ushort_t* apack = (ushort_t*)(ws);

        hipMemsetAsync(deg,    0, (size_t)kN * 4, stream);
        hipMemsetAsync(cnt,    0, (size_t)kN * 4, stream);
        hipMemsetAsync(loopat, 0, (size_t)kN * 4, stream);

        deg_kernel <<<(kE + 255) / 256, 256, 0, stream>>>(dst, ew, deg, loopat);
        scan_kernel<<<1, 256, 0, stream>>>(deg, loopat, offs);
        sort_kernel<<<(kE + 255) / 256, 256, 0, stream>>>(src, dst, ew, offs, cnt, ssrc, sew);

        pack_a_kernel<<<dim3(40, 157), 512, 0, stream>>>(x, kN, kESM, 40, xpack);
        pack_b_kernel<<<dim3(40, 16), 512, 0, stream>>>(Wl, Wr, 2048, 1024, 0, b1p);
        pack_b_kernel<<<dim3(64, 10), 512, 0, stream>>>(Wsl, Wsr, 1280, 1024, 1, b2p);

        gemm_mfma<<<dim3(16, 157), 256, 0, stream>>>(xpack, b1p, bl, 1024,
                                                     nullptr, xlr, kN, 2048, 40, 40, 0);

        gat2_kernel<<<kN, 256, 0, stream>>>(xlr, ssrc, sew, offs, loopat,
                                            We, att, bgat, hbuf);
        agg2_kernel<<<kN, 256, 0, stream>>>(hbuf, ssrc, offs, aggb);

        pack_a2_kernel<<<dim3(64, 157), 512, 0, stream>>>(aggb, hbuf, kN, apack);

        gemm_mfma<<<dim3(10, 157), 256, 0, stream>>>(apack, b2p, bsl, 1280,
                                                     x, (float*)d_out, kN, 1280, 64, 32, 1);

        ln_kernel<<<kN, 320, 0, stream>>>((float*)d_out, gamma, beta);
    } else {
        // ------------------ FALLBACK (round-2) ------------------
        size_t foff = 0;
        auto falloc = [&](size_t bytes) -> void* {
            void* p = ws + foff;
            foff = (foff + bytes + 255) & ~(size_t)255;
            return p;
        };
        int*   fdeg    = (int*)  falloc((size_t)kN * 4);
        int*   fcnt    = (int*)  falloc((size_t)kN * 4);
        int*   foffs   = (int*)  falloc((size_t)(kN + 1) * 4);
        float* floopat = (float*)falloc((size_t)kN * 4);
        int*   fssrc   = (int*)  falloc((size_t)kE * 4);
        float* fsew    = (float*)falloc((size_t)kE * 4);
        float* bufA    = (float*)falloc((size_t)kN * kHC * 4);
        float* bufB    = (float*)falloc((size_t)kN * kHC * 4);

        hipMemsetAsync(fdeg,    0, (size_t)kN * 4, stream);
        hipMemsetAsync(fcnt,    0, (size_t)kN * 4, stream);
        hipMemsetAsync(floopat, 0, (size_t)kN * 4, stream);

        deg_kernel <<<(kE + 255) / 256, 256, 0, stream>>>(dst, ew, fdeg, floopat);
        scan_kernel<<<1, 256, 0, stream>>>(fdeg, floopat, foffs);
        sort_kernel<<<(kE + 255) / 256, 256, 0, stream>>>(src, dst, ew, foffs, fcnt, fssrc, fsew);

        dim3 g1(kHC / BN, (kN + BM - 1) / BM);
        gemm_kernel<<<g1, 256, 0, stream>>>(x, Wl, nullptr, nullptr, bl, nullptr,
                                            bufA, kN, kHC, kESM, 0);
        gemm_kernel<<<g1, 256, 0, stream>>>(x, Wr, nullptr, nullptr, nullptr, nullptr,
                                            bufB, kN, kHC, kESM, 0);

        gat_kernel<<<kN, 256, 0, stream>>>(bufA, bufB, fssrc, fsew, foffs, floopat,
                                           We, att, bgat, bufB);
        agg_kernel<<<kN, 256, 0, stream>>>(bufB, fssrc, foffs, bufA);

        dim3 g2(kESM / BN, (kN + BM - 1) / BM);
        gemm_kernel<<<g2, 256, 0, stream>>>(bufA, Wsl, bufB, Wsr, bsl, x,
                                            (float*)d_out, kN, kESM, kHC, 1);

        ln_kernel<<<kN, 320, 0, stream>>>((float*)d_out, gamma, beta);
    }
}

// Round 7
// 1282.161 us; speedup vs baseline: 1.1654x; 1.1654x over previous
//
#include <hip/hip_runtime.h>
#include <hip/hip_bf16.h>
#include <math.h>

constexpr int kN   = 20000;
constexpr int kE   = 256000;
constexpr int kESM = 1280;
constexpr int kHC  = 1024;

typedef unsigned int  u32;
typedef unsigned short ushort_t;
typedef __bf16 bf16x8 __attribute__((ext_vector_type(8)));
typedef float  f32x4  __attribute__((ext_vector_type(4)));
typedef unsigned short u16x8 __attribute__((ext_vector_type(8)));
typedef unsigned short u16x4 __attribute__((ext_vector_type(4)));
typedef __attribute__((address_space(1))) const u32 gu32;
typedef __attribute__((address_space(3))) u32 lu32;

static __device__ __forceinline__ unsigned short f2bf_rne(float f) {
    u32 u = __float_as_uint(f);
    u32 r = (u + 0x7FFFu + ((u >> 16) & 1u)) >> 16;
    return (unsigned short)r;
}
static __device__ __forceinline__ float bf2f(unsigned short h) {
    return __uint_as_float(((u32)h) << 16);
}

// ---------------------------------------------------------------------------
// K1: degree + weighted-degree via atomics
// ---------------------------------------------------------------------------
__global__ __launch_bounds__(256) void deg_kernel(
    const int* __restrict__ dst, const float* __restrict__ ew,
    int* __restrict__ deg, float* __restrict__ wsum)
{
    int e = blockIdx.x * 256 + threadIdx.x;
    if (e < kE) {
        int d = dst[e];
        atomicAdd(&deg[d], 1);
        atomicAdd(&wsum[d], ew[e]);
    }
}

// ---------------------------------------------------------------------------
// K2: single-block scan, 1024 thr, shfl-based (3 barriers per 1024 chunk).
// offsets = exclusive-prefix; loop_attr = wsum/max(deg,1) in place.
// ---------------------------------------------------------------------------
__global__ __launch_bounds__(1024) void scan_kernel(
    const int* __restrict__ deg, float* __restrict__ loopat,
    int* __restrict__ offsets)
{
    __shared__ int wsum[16];
    const int tid = threadIdx.x, wave = tid >> 6, lane = tid & 63;
    int base = 0;
    if (tid == 0) offsets[0] = 0;
    for (int t0 = 0; t0 < kN; t0 += 1024) {
        const int i = t0 + tid;
        int d = (i < kN) ? deg[i] : 0;
        if (i < kN) loopat[i] = loopat[i] / fmaxf((float)d, 1.0f);
        int v = d;
#pragma unroll
        for (int off = 1; off < 64; off <<= 1) {
            int u = __shfl_up(v, off, 64);
            if (lane >= off) v += u;
        }
        if (lane == 63) wsum[wave] = v;
        __syncthreads();
        if (wave == 0) {
            int s = (lane < 16) ? wsum[lane] : 0;
#pragma unroll
            for (int off = 1; off < 16; off <<= 1) {
                int u = __shfl_up(s, off, 64);
                if (lane >= off) s += u;
            }
            if (lane < 16) wsum[lane] = s;
        }
        __syncthreads();
        const int prefix = base + (wave ? wsum[wave - 1] : 0);
        if (i < kN) offsets[i + 1] = prefix + v;
        base += wsum[15];
        __syncthreads();
    }
}

// ---------------------------------------------------------------------------
// K3: scatter edges into dst-sorted order
// ---------------------------------------------------------------------------
__global__ __launch_bounds__(256) void sort_kernel(
    const int* __restrict__ src, const int* __restrict__ dst,
    const float* __restrict__ ew, const int* __restrict__ offsets,
    int* __restrict__ cnt, int* __restrict__ ssrc, float* __restrict__ sew)
{
    int e = blockIdx.x * 256 + threadIdx.x;
    if (e < kE) {
        int d = dst[e];
        int p = offsets[d] + atomicAdd(&cnt[d], 1);
        ssrc[p] = src[e];
        sew[p]  = ew[e];
    }
}

// ===========================================================================
// FAST PATH: bf16x3 split MFMA GEMM with pre-packed operands.
// Packed tile layout per (mb/nb, kb): [hl(2)][g(4)][rc(128)][8] bf16 = 16 KB.
// A2 pack is COMPACT: kb >= 32 tiles are hi-only (8 KB).
// ===========================================================================

// pack A (fp32 [M][K], zero-pad rows >= M).  grid (NKB, MB), 512 thr.
__global__ __launch_bounds__(512) void pack_a_kernel(
    const float* __restrict__ A, int M, int K,
    int NKB, ushort_t* __restrict__ dst)
{
    const int kb = blockIdx.x, mb = blockIdx.y;
    const int tid = threadIdx.x;
    const int g = tid >> 7, r = tid & 127;
    const int row = mb * 128 + r;

    u16x8 hi, lo;
    if (row < M) {
        const float* src = A + (size_t)row * K + kb * 32 + g * 8;
        float4 v0 = *(const float4*)src;
        float4 v1 = *(const float4*)(src + 4);
        float vals[8] = {v0.x, v0.y, v0.z, v0.w, v1.x, v1.y, v1.z, v1.w};
#pragma unroll
        for (int j = 0; j < 8; ++j) {
            unsigned short h = f2bf_rne(vals[j]);
            hi[j] = h;
            lo[j] = f2bf_rne(vals[j] - bf2f(h));
        }
    } else {
#pragma unroll
        for (int j = 0; j < 8; ++j) { hi[j] = 0; lo[j] = 0; }
    }
    ushort_t* tb = dst + ((size_t)mb * NKB + kb) * 8192;
    *(u16x8*)&tb[0    + g * 1024 + r * 8] = hi;
    *(u16x8*)&tb[4096 + g * 1024 + r * 8] = lo;
}

// pack A2 = [agg(fp32) | h(bf16)] logical [M][2048], COMPACT layout:
// per-mb block = 32 full tiles (16KB) + 32 hi-only tiles (8KB) = 768KB.
constexpr size_t kA2Blk = 393216;   // ushorts per mb block
__global__ __launch_bounds__(512) void pack_a2_kernel(
    const float* __restrict__ agg, const ushort_t* __restrict__ hb,
    int M, ushort_t* __restrict__ dst)
{
    const int kb = blockIdx.x, mb = blockIdx.y;   // kb in [0,64)
    const int tid = threadIdx.x;
    const int g = tid >> 7, r = tid & 127;
    const int row = mb * 128 + r;

    if (kb < 32) {
        ushort_t* tb = dst + (size_t)mb * kA2Blk + (size_t)kb * 8192;
        u16x8 hi, lo;
        if (row < M) {
            const float* src = agg + (size_t)row * 1024 + kb * 32 + g * 8;
            float4 v0 = *(const float4*)src;
            float4 v1 = *(const float4*)(src + 4);
            float vals[8] = {v0.x, v0.y, v0.z, v0.w, v1.x, v1.y, v1.z, v1.w};
#pragma unroll
            for (int j = 0; j < 8; ++j) {
                unsigned short h = f2bf_rne(vals[j]);
                hi[j] = h;
                lo[j] = f2bf_rne(vals[j] - bf2f(h));
            }
        } else {
#pragma unroll
            for (int j = 0; j < 8; ++j) { hi[j] = 0; lo[j] = 0; }
        }
        *(u16x8*)&tb[0    + g * 1024 + r * 8] = hi;
        *(u16x8*)&tb[4096 + g * 1024 + r * 8] = lo;
    } else {
        ushort_t* tb = dst + (size_t)mb * kA2Blk + 262144 + (size_t)(kb - 32) * 4096;
        u16x8 hi;
        if (row < M) {
            hi = *(const u16x8*)&hb[(size_t)row * 1024 + (kb - 32) * 32 + g * 8];
        } else {
#pragma unroll
            for (int j = 0; j < 8; ++j) hi[j] = 0;
        }
        *(u16x8*)&tb[g * 1024 + r * 8] = hi;
    }
}

// pack B. mode 0 (col-split): B(k,n) = n<split ? B1[k][n] : B2[k][n-split]
//         mode 1 (row-split): B(k,n) = k<split ? B1[k][n] : B2[(k-split)][n]
__global__ __launch_bounds__(512) void pack_b_kernel(
    const float* __restrict__ B1, const float* __restrict__ B2,
    int N, int split, int mode, ushort_t* __restrict__ dst)
{
    const int kb = blockIdx.x, nb = blockIdx.y;
    const int NKB = gridDim.x;
    const int tid = threadIdx.x;
    const int g = tid >> 7, c = tid & 127;
    const int n = nb * 128 + c;

    u16x8 hi, lo;
#pragma unroll
    for (int j = 0; j < 8; ++j) {
        int k = kb * 32 + g * 8 + j;
        float v;
        if (mode == 0) {
            v = (n < split) ? B1[(size_t)k * split + n]
                            : B2[(size_t)k * (N - split) + (n - split)];
        } else {
            v = (k < split) ? B1[(size_t)k * N + n]
                            : B2[(size_t)(k - split) * N + n];
        }
        unsigned short h = f2bf_rne(v);
        hi[j] = h;
        lo[j] = f2bf_rne(v - bf2f(h));
    }
    ushort_t* tb = dst + ((size_t)nb * NKB + kb) * 8192;
    *(u16x8*)&tb[0    + g * 1024 + c * 8] = hi;
    *(u16x8*)&tb[4096 + g * 1024 + c * 8] = lo;
}

// bf16x3 MFMA GEMM (round-5 structure): C = epi(Ahi*Bhi + Ahi*Blo + Alo*Bhi).
// 128x128 tile, BK=32, 4 waves (2x2), 4x4 16x16x32 frags/wave, 32KB LDS.
// Phase 2 (kb >= nkb_full): A-lo known-zero -> compact hi-only 8KB A tiles.
// Split-output mode (Cbf != null): col<1024 -> bf16 Cbf, col>=1024 -> fp32 C.
// XCD-aware bijective block swizzle (m204) for A-panel L2 locality.
__global__ __launch_bounds__(256) void gemm_mfma(
    const ushort_t* __restrict__ Ap, const ushort_t* __restrict__ Bp,
    const float* __restrict__ bias, int biasN,
    const float* __restrict__ resid, float* __restrict__ C,
    ushort_t* __restrict__ Cbf,
    int M, int N, int NKB, int nkb_full, int do_relu)
{
    __shared__ ushort_t sb[16384];   // 32KB: A tile [0..8191], B tile [8192..]
    const int tid  = threadIdx.x;
    const int wid  = tid >> 6;
    const int lane = tid & 63;
    const int l15 = lane & 15, l4 = lane >> 4;

    const int nwg = gridDim.x * gridDim.y;
    const int lin = blockIdx.y * gridDim.x + blockIdx.x;
    const int q = nwg >> 3, r = nwg & 7;
    const int xcd = lin & 7, pos = lin >> 3;
    const int swz = (xcd < r ? xcd * (q + 1) : r * (q + 1) + (xcd - r) * q) + pos;
    const int mb = swz / gridDim.x, nb = swz % gridDim.x;
    const int wr = wid >> 1, wc = wid & 1;

    f32x4 acc[4][4];
#pragma unroll
    for (int i = 0; i < 4; ++i)
#pragma unroll
        for (int j = 0; j < 4; ++j) acc[i][j] = (f32x4){0.f, 0.f, 0.f, 0.f};

    const size_t a_blk = (size_t)nkb_full * 8192 + (size_t)(NKB - nkb_full) * 4096;
    const char* at = (const char*)(Ap + (size_t)mb * a_blk);
    const char* bt = (const char*)(Bp + (size_t)nb * NKB * 8192);

    // phase 1: full split (3 products per frag)
    for (int kb = 0; kb < nkb_full; ++kb) {
        const char* atk = at + (size_t)kb * 16384;
        const char* btk = bt + (size_t)kb * 16384;
#pragma unroll
        for (int c = 0; c < 4; ++c) {
            __builtin_amdgcn_global_load_lds(
                (gu32*)(atk + c * 4096 + tid * 16),
                (lu32*)&sb[c * 2048 + wid * 512], 16, 0, 0);
            __builtin_amdgcn_global_load_lds(
                (gu32*)(btk + c * 4096 + tid * 16),
                (lu32*)&sb[8192 + c * 2048 + wid * 512], 16, 0, 0);
        }
        __syncthreads();

        bf16x8 af[2][4], bv[2][4];
#pragma unroll
        for (int hl = 0; hl < 2; ++hl)
#pragma unroll
            for (int m = 0; m < 4; ++m)
                af[hl][m] = *(const bf16x8*)&sb[hl * 4096 + l4 * 1024 + (wr * 64 + m * 16 + l15) * 8];
#pragma unroll
        for (int hl = 0; hl < 2; ++hl)
#pragma unroll
            for (int n = 0; n < 4; ++n)
                bv[hl][n] = *(const bf16x8*)&sb[8192 + hl * 4096 + l4 * 1024 + (wc * 64 + n * 16 + l15) * 8];

#pragma unroll
        for (int m = 0; m < 4; ++m)
#pragma unroll
            for (int n = 0; n < 4; ++n) {
                acc[m][n] = __builtin_amdgcn_mfma_f32_16x16x32_bf16(af[0][m], bv[0][n], acc[m][n], 0, 0, 0);
                acc[m][n] = __builtin_amdgcn_mfma_f32_16x16x32_bf16(af[0][m], bv[1][n], acc[m][n], 0, 0, 0);
                acc[m][n] = __builtin_amdgcn_mfma_f32_16x16x32_bf16(af[1][m], bv[0][n], acc[m][n], 0, 0, 0);
            }
        __syncthreads();
    }

    // phase 2: A-lo known zero -> compact 8KB A tiles, 2 products per frag
    for (int kb = nkb_full; kb < NKB; ++kb) {
        const char* atk = at + (size_t)nkb_full * 16384 + (size_t)(kb - nkb_full) * 8192;
        const char* btk = bt + (size_t)kb * 16384;
#pragma unroll
        for (int c = 0; c < 2; ++c) {
            __builtin_amdgcn_global_load_lds(
                (gu32*)(atk + c * 4096 + tid * 16),
                (lu32*)&sb[c * 2048 + wid * 512], 16, 0, 0);
        }
#pragma unroll
        for (int c = 0; c < 4; ++c) {
            __builtin_amdgcn_global_load_lds(
                (gu32*)(btk + c * 4096 + tid * 16),
                (lu32*)&sb[8192 + c * 2048 + wid * 512], 16, 0, 0);
        }
        __syncthreads();

        bf16x8 af0[4], bv[2][4];
#pragma unroll
        for (int m = 0; m < 4; ++m)
            af0[m] = *(const bf16x8*)&sb[l4 * 1024 + (wr * 64 + m * 16 + l15) * 8];
#pragma unroll
        for (int hl = 0; hl < 2; ++hl)
#pragma unroll
            for (int n = 0; n < 4; ++n)
                bv[hl][n] = *(const bf16x8*)&sb[8192 + hl * 4096 + l4 * 1024 + (wc * 64 + n * 16 + l15) * 8];

#pragma unroll
        for (int m = 0; m < 4; ++m)
#pragma unroll
            for (int n = 0; n < 4; ++n) {
                acc[m][n] = __builtin_amdgcn_mfma_f32_16x16x32_bf16(af0[m], bv[0][n], acc[m][n], 0, 0, 0);
                acc[m][n] = __builtin_amdgcn_mfma_f32_16x16x32_bf16(af0[m], bv[1][n], acc[m][n], 0, 0, 0);
            }
        __syncthreads();
    }

    const int row_w = mb * 128 + wr * 64;
    const int col_w = nb * 128 + wc * 64;
    if (Cbf) {
        // split mode: col<1024 -> bf16 Cbf (with bias), col>=1024 -> fp32 C (no bias)
        const bool isxl = (col_w < 1024);   // uniform across the wave's 64-col tile
#pragma unroll
        for (int m = 0; m < 4; ++m) {
#pragma unroll
            for (int n = 0; n < 4; ++n) {
                const int col = col_w + n * 16 + l15;
#pragma unroll
                for (int j = 0; j < 4; ++j) {
                    const int row = row_w + m * 16 + l4 * 4 + j;
                    if (row < M) {
                        float v = acc[m][n][j];
                        if (isxl) {
                            v += bias[col];
                            Cbf[(size_t)row * 1024 + col] = f2bf_rne(v);
                        } else {
                            C[(size_t)row * 1024 + (col - 1024)] = v;
                        }
                    }
                }
            }
        }
    } else {
#pragma unroll
        for (int m = 0; m < 4; ++m) {
#pragma unroll
            for (int n = 0; n < 4; ++n) {
                const int col = col_w + n * 16 + l15;
#pragma unroll
                for (int j = 0; j < 4; ++j) {
                    const int row = row_w + m * 16 + l4 * 4 + j;
                    if (row < M) {
                        float v = acc[m][n][j];
                        if (bias && col < biasN) v += bias[col];
                        if (do_relu) v = fmaxf(v, 0.f);
                        if (resid) v += resid[(size_t)row * N + col];
                        C[(size_t)row * N + col] = v;
                    }
                }
            }
        }
    }
}

// fused GAT (fast path): xl bf16 [N][1024], xr fp32 [N][1024], h out bf16.
__global__ __launch_bounds__(256) void gat2_kernel(
    const ushort_t* __restrict__ xlb, const float* __restrict__ xrb,
    const int* __restrict__ ssrc, const float* __restrict__ sew,
    const int* __restrict__ offsets, const float* __restrict__ loopat,
    const float* __restrict__ We, const float* __restrict__ att,
    const float* __restrict__ bgat, ushort_t* __restrict__ hout)
{
    const int n = blockIdx.x;
    const int base = threadIdx.x * 4;

    const float4 xr4 = *(const float4*)&xrb[(size_t)n * 1024 + base];
    const float4 We4 = *(const float4*)&We[base];
    const float4 at4 = *(const float4*)&att[base];

    float M = -INFINITY, D = 0.f;
    float4 acc = make_float4(0.f, 0.f, 0.f, 0.f);

    const int beg = offsets[n], end = offsets[n + 1];
    for (int e = beg; e <= end; ++e) {   // inclusive: last iter = self-loop
        int s; float w;
        if (e < end) { s = ssrc[e]; w = sew[e]; }
        else         { s = n;       w = loopat[n]; }

        const u16x4 xh = *(const u16x4*)&xlb[(size_t)s * 1024 + base];
        float4 xls;
        xls.x = bf2f(xh[0]); xls.y = bf2f(xh[1]);
        xls.z = bf2f(xh[2]); xls.w = bf2f(xh[3]);
        float m0 = xls.x + xr4.x + w * We4.x;
        float m1 = xls.y + xr4.y + w * We4.y;
        float m2 = xls.z + xr4.z + w * We4.z;
        float m3 = xls.w + xr4.w + w * We4.w;
        m0 = (m0 >= 0.f) ? m0 : 0.2f * m0;
        m1 = (m1 >= 0.f) ? m1 : 0.2f * m1;
        m2 = (m2 >= 0.f) ? m2 : 0.2f * m2;
        m3 = (m3 >= 0.f) ? m3 : 0.2f * m3;
        float p = m0 * at4.x + m1 * at4.y + m2 * at4.z + m3 * at4.w;
#pragma unroll
        for (int o = 32; o >= 1; o >>= 1) p += __shfl_xor(p, o, 64);

        float newM  = fmaxf(M, p);
        float scale = __expf(M - newM);
        float wexp  = __expf(p - newM);
        D     = D * scale + wexp;
        acc.x = acc.x * scale + wexp * xls.x;
        acc.y = acc.y * scale + wexp * xls.y;
        acc.z = acc.z * scale + wexp * xls.z;
        acc.w = acc.w * scale + wexp * xls.w;
        M = newM;
    }

    const float inv = 1.0f / (D + 1e-16f);
    float g0 = acc.x * inv + bgat[base + 0];
    float g1 = acc.y * inv + bgat[base + 1];
    float g2 = acc.z * inv + bgat[base + 2];
    float g3 = acc.w * inv + bgat[base + 3];
    u16x4 hv;
    hv[0] = f2bf_rne((g0 > 0.f) ? g0 : expm1f(g0));
    hv[1] = f2bf_rne((g1 > 0.f) ? g1 : expm1f(g1));
    hv[2] = f2bf_rne((g2 > 0.f) ? g2 : expm1f(g2));
    hv[3] = f2bf_rne((g3 > 0.f) ? g3 : expm1f(g3));
    *(u16x4*)&hout[(size_t)n * 1024 + base] = hv;
}

// agg (fast path): mean of bf16 h[src] rows -> fp32 agg
__global__ __launch_bounds__(256) void agg2_kernel(
    const ushort_t* __restrict__ hb, const int* __restrict__ ssrc,
    const int* __restrict__ offsets, float* __restrict__ aggout)
{
    const int n = blockIdx.x;
    const int base = threadIdx.x * 4;
    float4 a = make_float4(0.f, 0.f, 0.f, 0.f);
    const int beg = offsets[n], end = offsets[n + 1];
    for (int e = beg; e < end; ++e) {
        const u16x4 hv = *(const u16x4*)&hb[(size_t)ssrc[e] * 1024 + base];
        a.x += bf2f(hv[0]); a.y += bf2f(hv[1]);
        a.z += bf2f(hv[2]); a.w += bf2f(hv[3]);
    }
    const float inv = 1.0f / fmaxf((float)(end - beg), 1.0f);
    a.x *= inv; a.y *= inv; a.z *= inv; a.w *= inv;
    *(float4*)&aggout[(size_t)n * 1024 + base] = a;
}

// ---------------------------------------------------------------------------
// LayerNorm over last dim (1280), in-place. 320 threads x float4 per row.
// ---------------------------------------------------------------------------
__global__ __launch_bounds__(320) void ln_kernel(
    float* __restrict__ z, const float* __restrict__ gamma,
    const float* __restrict__ beta)
{
    const int r = blockIdx.x;
    const int t = threadIdx.x;
    const int wave = t >> 6, lane = t & 63;
    __shared__ float red[5];

    float4 v = *(const float4*)&z[(size_t)r * kESM + t * 4];
    float s = v.x + v.y + v.z + v.w;
#pragma unroll
    for (int o = 32; o >= 1; o >>= 1) s += __shfl_xor(s, o, 64);
    if (lane == 0) red[wave] = s;
    __syncthreads();
    s = red[0] + red[1] + red[2] + red[3] + red[4];
    const float mu = s * (1.0f / (float)kESM);

    float dx = v.x - mu, dy = v.y - mu, dz = v.z - mu, dw = v.w - mu;
    float q = dx * dx + dy * dy + dz * dz + dw * dw;
#pragma unroll
    for (int o = 32; o >= 1; o >>= 1) q += __shfl_xor(q, o, 64);
    __syncthreads();
    if (lane == 0) red[wave] = q;
    __syncthreads();
    q = red[0] + red[1] + red[2] + red[3] + red[4];
    const float rstd = rsqrtf(q * (1.0f / (float)kESM) + 1e-5f);

    const float4 g4 = *(const float4*)&gamma[t * 4];
    const float4 b4 = *(const float4*)&beta[t * 4];
    float4 o;
    o.x = dx * rstd * g4.x + b4.x;
    o.y = dy * rstd * g4.y + b4.y;
    o.z = dz * rstd * g4.z + b4.z;
    o.w = dw * rstd * g4.w + b4.w;
    *(float4*)&z[(size_t)r * kESM + t * 4] = o;
}

// ===========================================================================
// FALLBACK PATH (round-2, known-pass): fp32 vector GEMM + fp32 gat/agg
// ===========================================================================
#define BM 128
#define BN 128
#define BK 16

__global__ __launch_bounds__(256) void gemm_kernel(
    const float* __restrict__ A,  const float* __restrict__ B,
    const float* __restrict__ A2, const float* __restrict__ B2,
    const float* __restrict__ bias, const float* __restrict__ resid,
    float* __restrict__ C, int M, int N, int K, int do_relu)
{
    __shared__ float As[BK][BM];
    __shared__ float Bs[BK][BN];

    const int tid = threadIdx.x;
    const int bm = blockIdx.y, bn = blockIdx.x;
    const int row0 = bm * BM, col0 = bn * BN;
    const int tx = tid & 15, ty = tid >> 4;

    float acc[8][8];
#pragma unroll
    for (int i = 0; i < 8; ++i)
#pragma unroll
        for (int j = 0; j < 8; ++j) acc[i][j] = 0.0f;

    const int arow  = tid >> 1;
    const int akoff = (tid & 1) * 8;
    const int bkr   = tid >> 4;
    const int bcol  = (tid & 15) * 8;

    for (int pair = 0; pair < 2; ++pair) {
        const float* Ap = pair ? A2 : A;
        const float* Bp = pair ? B2 : B;
        if (!Ap) break;
        for (int k0 = 0; k0 < K; k0 += BK) {
            float4 a0 = make_float4(0.f, 0.f, 0.f, 0.f);
            float4 a1 = a0;
            int gr = row0 + arow;
            if (gr < M) {
                const float* aptr = Ap + (size_t)gr * K + k0 + akoff;
                a0 = *(const float4*)aptr;
                a1 = *(const float4*)(aptr + 4);
            }
            const float* bptr = Bp + (size_t)(k0 + bkr) * N + col0 + bcol;
            float4 b0 = *(const float4*)bptr;
            float4 b1 = *(const float4*)(bptr + 4);

            __syncthreads();
            As[akoff + 0][arow] = a0.x;
            As[akoff + 1][arow] = a0.y;
            As[akoff + 2][arow] = a0.z;
            As[akoff + 3][arow] = a0.w;
            As[akoff + 4][arow] = a1.x;
            As[akoff + 5][arow] = a1.y;
            As[akoff + 6][arow] = a1.z;
            As[akoff + 7][arow] = a1.w;
            *(float4*)&Bs[bkr][bcol]     = b0;
            *(float4*)&Bs[bkr][bcol + 4] = b1;
            __syncthreads();

#pragma unroll
            for (int kk = 0; kk < BK; ++kk) {
                float4 a0r = *(const float4*)&As[kk][ty * 8];
                float4 a1r = *(const float4*)&As[kk][ty * 8 + 4];
                float4 b0r = *(const float4*)&Bs[kk][tx * 4];
                float4 b1r = *(const float4*)&Bs[kk][64 + tx * 4];
                float ar[8] = {a0r.x, a0r.y, a0r.z, a0r.w, a1r.x, a1r.y, a1r.z, a1r.w};
                float br[8] = {b0r.x, b0r.y, b0r.z, b0r.w, b1r.x, b1r.y, b1r.z, b1r.w};
#pragma unroll
                for (int i = 0; i < 8; ++i)
#pragma unroll
                    for (int j = 0; j < 8; ++j)
                        acc[i][j] = fmaf(ar[i], br[j], acc[i][j]);
            }
        }
    }

#pragma unroll
    for (int i = 0; i < 8; ++i) {
        int gr = row0 + ty * 8 + i;
        if (gr >= M) break;
#pragma unroll
        for (int half = 0; half < 2; ++half) {
            int gc = col0 + half * 64 + tx * 4;
            float4 out;
            float* o = &out.x;
            const float* rrow = resid ? (resid + (size_t)gr * N + gc) : nullptr;
#pragma unroll
            for (int j = 0; j < 4; ++j) {
                float v = acc[i][half * 4 + j];
                if (bias) v += bias[gc + j];
                if (do_relu) v = fmaxf(v, 0.0f);
                if (rrow) v += rrow[j];
                o[j] = v;
            }
            *(float4*)&C[(size_t)gr * N + gc] = out;
        }
    }
}

__global__ __launch_bounds__(256) void gat_kernel(
    const float* __restrict__ xl, const float* __restrict__ xr,
    const int* __restrict__ ssrc, const float* __restrict__ sew,
    const int* __restrict__ offsets, const float* __restrict__ loopat,
    const float* __restrict__ We, const float* __restrict__ att,
    const float* __restrict__ bgat, float* __restrict__ hout)
{
    const int n = blockIdx.x;
    const int base = threadIdx.x * 4;

    const float4 xr4 = *(const float4*)&xr[(size_t)n * kHC + base];
    const float4 We4 = *(const float4*)&We[base];
    const float4 at4 = *(const float4*)&att[base];

    float M = -INFINITY, D = 0.f;
    float4 acc = make_float4(0.f, 0.f, 0.f, 0.f);

    const int beg = offsets[n], end = offsets[n + 1];
    for (int e = beg; e <= end; ++e) {
        int s; float w;
        if (e < end) { s = ssrc[e]; w = sew[e]; }
        else         { s = n;       w = loopat[n]; }

        const float4 xls = *(const float4*)&xl[(size_t)s * kHC + base];
        float m0 = xls.x + xr4.x + w * We4.x;
        float m1 = xls.y + xr4.y + w * We4.y;
        float m2 = xls.z + xr4.z + w * We4.z;
        float m3 = xls.w + xr4.w + w * We4.w;
        m0 = (m0 >= 0.f) ? m0 : 0.2f * m0;
        m1 = (m1 >= 0.f) ? m1 : 0.2f * m1;
        m2 = (m2 >= 0.f) ? m2 : 0.2f * m2;
        m3 = (m3 >= 0.f) ? m3 : 0.2f * m3;
        float p = m0 * at4.x + m1 * at4.y + m2 * at4.z + m3 * at4.w;
#pragma unroll
        for (int o = 32; o >= 1; o >>= 1) p += __shfl_xor(p, o, 64);

        float newM  = fmaxf(M, p);
        float scale = __expf(M - newM);
        float wexp  = __expf(p - newM);
        D     = D * scale + wexp;
        acc.x = acc.x * scale + wexp * xls.x;
        acc.y = acc.y * scale + wexp * xls.y;
        acc.z = acc.z * scale + wexp * xls.z;
        acc.w = acc.w * scale + wexp * xls.w;
        M = newM;
    }

    const float inv = 1.0f / (D + 1e-16f);
    float g0 = acc.x * inv + bgat[base + 0];
    float g1 = acc.y * inv + bgat[base + 1];
    float g2 = acc.z * inv + bgat[base + 2];
    float g3 = acc.w * inv + bgat[base + 3];
    float4 hv;
    hv.x = (g0 > 0.f) ? g0 : expm1f(g0);
    hv.y = (g1 > 0.f) ? g1 : expm1f(g1);
    hv.z = (g2 > 0.f) ? g2 : expm1f(g2);
    hv.w = (g3 > 0.f) ? g3 : expm1f(g3);
    *(float4*)&hout[(size_t)n * kHC + base] = hv;
}

__global__ __launch_bounds__(256) void agg_kernel(
    const float* __restrict__ h, const int* __restrict__ ssrc,
    const int* __restrict__ offsets, float* __restrict__ aggout)
{
    const int n = blockIdx.x;
    const int base = threadIdx.x * 4;
    float4 a = make_float4(0.f, 0.f, 0.f, 0.f);
    const int beg = offsets[n], end = offsets[n + 1];
    for (int e = beg; e < end; ++e) {
        const float4 hv = *(const float4*)&h[(size_t)ssrc[e] * kHC + base];
        a.x += hv.x; a.y += hv.y; a.z += hv.z; a.w += hv.w;
    }
    const float inv = 1.0f / fmaxf((float)(end - beg), 1.0f);
    a.x *= inv; a.y *= inv; a.z *= inv; a.w *= inv;
    *(float4*)&aggout[(size_t)n * kHC + base] = a;
}

// Old 256-thread scan kept for fallback path
__global__ __launch_bounds__(256) void scan_kernel_fb(
    const int* __restrict__ deg, float* __restrict__ loopat,
    int* __restrict__ offsets)
{
    __shared__ int s[256];
    int tid = threadIdx.x;
    int base = 0;
    if (tid == 0) offsets[0] = 0;
    for (int t0 = 0; t0 < kN; t0 += 256) {
        int i = t0 + tid;
        int d = (i < kN) ? deg[i] : 0;
        if (i < kN) {
            float w = loopat[i];
            loopat[i] = w / fmaxf((float)d, 1.0f);
        }
        s[tid] = d;
        int v = d;
        for (int off = 1; off < 256; off <<= 1) {
            __syncthreads();
            int add = (tid >= off) ? s[tid - off] : 0;
            __syncthreads();
            v += add;
            s[tid] = v;
        }
        __syncthreads();
        if (i < kN) offsets[i + 1] = base + v;
        base += s[255];
        __syncthreads();
    }
}

// ---------------------------------------------------------------------------
extern "C" void kernel_launch(void* const* d_in, const int* in_sizes, int n_in,
                              void* d_out, int out_size, void* d_ws, size_t ws_size,
                              hipStream_t stream)
{
    const float* x     = (const float*)d_in[0];
    const int*   ei    = (const int*)  d_in[1];
    const float* ew    = (const float*)d_in[2];
    const float* Wl    = (const float*)d_in[3];
    const float* bl    = (const float*)d_in[4];
    const float* Wr    = (const float*)d_in[5];
    const float* We    = (const float*)d_in[6];
    const float* att   = (const float*)d_in[7];
    const float* bgat  = (const float*)d_in[8];
    const float* Wsl   = (const float*)d_in[9];
    const float* bsl   = (const float*)d_in[10];
    const float* Wsr   = (const float*)d_in[11];
    const float* gamma = (const float*)d_in[12];
    const float* beta  = (const float*)d_in[13];
    const int* src = ei;
    const int* dst = ei + kE;
    char* ws = (char*)d_ws;

    // fast-path layout (bytes):
    // [xlb 41MB][xrb 82MB][b1p 10.5MB][xpack 103MB][hbuf 41MB][b2p 10.5MB][small]
    // aliases: aggb over xpack (dead after GEMM1); apack (compact, 123.5MB)
    //          over xlb+xrb+b1p (all dead by pack_a2 time).
    const size_t SZ_XLB  = (size_t)kN * 1024 * 2;            //  40,960,000
    const size_t SZ_XRB  = (size_t)kN * 1024 * 4;            //  81,920,000
    const size_t SZ_B1   = (size_t)16 * 40 * 16384;          //  10,485,760
    const size_t SZ_XPK  = (size_t)157 * 40 * 16384;         // 102,891,520
    const size_t SZ_HBF  = (size_t)kN * 1024 * 2;            //  40,960,000
    const size_t SZ_B2   = (size_t)10 * 64 * 16384;          //  10,485,760
    const size_t OFF_XRB = SZ_XLB;
    const size_t OFF_B1  = OFF_XRB + SZ_XRB;
    const size_t OFF_XPK = OFF_B1 + SZ_B1;
    const size_t OFF_HBF = OFF_XPK + SZ_XPK;
    const size_t OFF_B2  = OFF_HBF + SZ_HBF;
    size_t off = OFF_B2 + SZ_B2;
    auto salloc = [&](size_t bytes) -> void* {
        void* p = ws + off;
        off = (off + bytes + 255) & ~(size_t)255;
        return p;
    };
    int*   deg    = (int*)  salloc((size_t)kN * 4);
    int*   cnt    = (int*)  salloc((size_t)kN * 4);
    int*   offs   = (int*)  salloc((size_t)(kN + 1) * 4);
    float* loopat = (float*)salloc((size_t)kN * 4);
    int*   ssrc   = (int*)  salloc((size_t)kE * 4);
    float* sew    = (float*)salloc((size_t)kE * 4);
    const size_t FAST_TOTAL = off;   // ~290 MB

    if (ws_size >= FAST_TOTAL) {
        // ------------------ FAST PATH ------------------
        ushort_t* xlb   = (ushort_t*)(ws);
        float*    xrb   = (float*)   (ws + OFF_XRB);
        ushort_t* b1p   = (ushort_t*)(ws + OFF_B1);
        ushort_t* xpack = (ushort_t*)(ws + OFF_XPK);
        ushort_t* hbuf  = (ushort_t*)(ws + OFF_HBF);
        ushort_t* b2p   = (ushort_t*)(ws + OFF_B2);
        float*    aggb  = (float*)   (ws + OFF_XPK);  // over dead xpack (80<=103MB)
        ushort_t* apack = (ushort_t*)(ws);            // compact 123.5MB over dead xlb+xrb+b1p

        hipMemsetAsync(deg,    0, (size_t)kN * 4, stream);
        hipMemsetAsync(cnt,    0, (size_t)kN * 4, stream);
        hipMemsetAsync(loopat, 0, (size_t)kN * 4, stream);

        deg_kernel <<<(kE + 255) / 256, 256, 0, stream>>>(dst, ew, deg, loopat);
        scan_kernel<<<1, 1024, 0, stream>>>(deg, loopat, offs);
        sort_kernel<<<(kE + 255) / 256, 256, 0, stream>>>(src, dst, ew, offs, cnt, ssrc, sew);

        pack_a_kernel<<<dim3(40, 157), 512, 0, stream>>>(x, kN, kESM, 40, xpack);
        pack_b_kernel<<<dim3(40, 16), 512, 0, stream>>>(Wl, Wr, 2048, 1024, 0, b1p);
        pack_b_kernel<<<dim3(64, 10), 512, 0, stream>>>(Wsl, Wsr, 1280, 1024, 1, b2p);

        // GEMM1 split-output: xl -> bf16 xlb (+bias), xr -> fp32 xrb
        gemm_mfma<<<dim3(16, 157), 256, 0, stream>>>(xpack, b1p, bl, 1024,
                                                     nullptr, xrb, xlb,
                                                     kN, 2048, 40, 40, 0);

        gat2_kernel<<<kN, 256, 0, stream>>>(xlb, xrb, ssrc, sew, offs, loopat,
                                            We, att, bgat, hbuf);
        agg2_kernel<<<kN, 256, 0, stream>>>(hbuf, ssrc, offs, aggb);

        pack_a2_kernel<<<dim3(64, 157), 512, 0, stream>>>(aggb, hbuf, kN, apack);

        gemm_mfma<<<dim3(10, 157), 256, 0, stream>>>(apack, b2p, bsl, 1280,
                                                     x, (float*)d_out, nullptr,
                                                     kN, 1280, 64, 32, 1);

        ln_kernel<<<kN, 320, 0, stream>>>((float*)d_out, gamma, beta);
    } else {
        // ------------------ FALLBACK (round-2) ------------------
        size_t foff = 0;
        auto falloc = [&](size_t bytes) -> void* {
            void* p = ws + foff;
            foff = (foff + bytes + 255) & ~(size_t)255;
            return p;
        };
        int*   fdeg    = (int*)  falloc((size_t)kN * 4);
        int*   fcnt    = (int*)  falloc((size_t)kN * 4);
        int*   foffs   = (int*)  falloc((size_t)(kN + 1) * 4);
        float* floopat = (float*)falloc((size_t)kN * 4);
        int*   fssrc   = (int*)  falloc((size_t)kE * 4);
        float* fsew    = (float*)falloc((size_t)kE * 4);
        float* bufA    = (float*)falloc((size_t)kN * kHC * 4);
        float* bufB    = (float*)falloc((size_t)kN * kHC * 4);

        hipMemsetAsync(fdeg,    0, (size_t)kN * 4, stream);
        hipMemsetAsync(fcnt,    0, (size_t)kN * 4, stream);
        hipMemsetAsync(floopat, 0, (size_t)kN * 4, stream);

        deg_kernel <<<(kE + 255) / 256, 256, 0, stream>>>(dst, ew, fdeg, floopat);
        scan_kernel_fb<<<1, 256, 0, stream>>>(fdeg, floopat, foffs);
        sort_kernel<<<(kE + 255) / 256, 256, 0, stream>>>(src, dst, ew, foffs, fcnt, fssrc, fsew);

        dim3 g1(kHC / BN, (kN + BM - 1) / BM);
        gemm_kernel<<<g1, 256, 0, stream>>>(x, Wl, nullptr, nullptr, bl, nullptr,
                                            bufA, kN, kHC, kESM, 0);
        gemm_kernel<<<g1, 256, 0, stream>>>(x, Wr, nullptr, nullptr, nullptr, nullptr,
                                            bufB, kN, kHC, kESM, 0);

        gat_kernel<<<kN, 256, 0, stream>>>(bufA, bufB, fssrc, fsew, foffs, floopat,
                                           We, att, bgat, bufB);
        agg_kernel<<<kN, 256, 0, stream>>>(bufB, fssrc, foffs, bufA);

        dim3 g2(kESM / BN, (kN + BM - 1) / BM);
        gemm_kernel<<<g2, 256, 0, stream>>>(bufA, Wsl, bufB, Wsr, bsl, x,
                                            (float*)d_out, kN, kESM, kHC, 1);

        ln_kernel<<<kN, 320, 0, stream>>>((float*)d_out, gamma, beta);
    }
}

// Round 10
// 1275.763 us; speedup vs baseline: 1.1713x; 1.0050x over previous
//
#include <hip/hip_runtime.h>
#include <hip/hip_bf16.h>
#include <math.h>

constexpr int kN   = 20000;
constexpr int kE   = 256000;
constexpr int kESM = 1280;
constexpr int kHC  = 1024;

typedef unsigned int  u32;
typedef unsigned short ushort_t;
typedef __bf16 bf16x8 __attribute__((ext_vector_type(8)));
typedef float  f32x4  __attribute__((ext_vector_type(4)));
typedef unsigned short u16x8 __attribute__((ext_vector_type(8)));
typedef unsigned short u16x4 __attribute__((ext_vector_type(4)));
typedef __attribute__((address_space(1))) const u32 gu32;
typedef __attribute__((address_space(3))) u32 lu32;

static __device__ __forceinline__ unsigned short f2bf_rne(float f) {
    u32 u = __float_as_uint(f);
    u32 r = (u + 0x7FFFu + ((u >> 16) & 1u)) >> 16;
    return (unsigned short)r;
}
static __device__ __forceinline__ float bf2f(unsigned short h) {
    return __uint_as_float(((u32)h) << 16);
}

// ---------------------------------------------------------------------------
// K1: degree + weighted-degree via atomics
// ---------------------------------------------------------------------------
__global__ __launch_bounds__(256) void deg_kernel(
    const int* __restrict__ dst, const float* __restrict__ ew,
    int* __restrict__ deg, float* __restrict__ wsum)
{
    int e = blockIdx.x * 256 + threadIdx.x;
    if (e < kE) {
        int d = dst[e];
        atomicAdd(&deg[d], 1);
        atomicAdd(&wsum[d], ew[e]);
    }
}

// ---------------------------------------------------------------------------
// K2: single-block scan, 1024 thr, shfl-based.
// ---------------------------------------------------------------------------
__global__ __launch_bounds__(1024) void scan_kernel(
    const int* __restrict__ deg, float* __restrict__ loopat,
    int* __restrict__ offsets)
{
    __shared__ int wsum[16];
    const int tid = threadIdx.x, wave = tid >> 6, lane = tid & 63;
    int base = 0;
    if (tid == 0) offsets[0] = 0;
    for (int t0 = 0; t0 < kN; t0 += 1024) {
        const int i = t0 + tid;
        int d = (i < kN) ? deg[i] : 0;
        if (i < kN) loopat[i] = loopat[i] / fmaxf((float)d, 1.0f);
        int v = d;
#pragma unroll
        for (int off = 1; off < 64; off <<= 1) {
            int u = __shfl_up(v, off, 64);
            if (lane >= off) v += u;
        }
        if (lane == 63) wsum[wave] = v;
        __syncthreads();
        if (wave == 0) {
            int s = (lane < 16) ? wsum[lane] : 0;
#pragma unroll
            for (int off = 1; off < 16; off <<= 1) {
                int u = __shfl_up(s, off, 64);
                if (lane >= off) s += u;
            }
            if (lane < 16) wsum[lane] = s;
        }
        __syncthreads();
        const int prefix = base + (wave ? wsum[wave - 1] : 0);
        if (i < kN) offsets[i + 1] = prefix + v;
        base += wsum[15];
        __syncthreads();
    }
}

// ---------------------------------------------------------------------------
// K3: scatter edges into dst-sorted order
// ---------------------------------------------------------------------------
__global__ __launch_bounds__(256) void sort_kernel(
    const int* __restrict__ src, const int* __restrict__ dst,
    const float* __restrict__ ew, const int* __restrict__ offsets,
    int* __restrict__ cnt, int* __restrict__ ssrc, float* __restrict__ sew)
{
    int e = blockIdx.x * 256 + threadIdx.x;
    if (e < kE) {
        int d = dst[e];
        int p = offsets[d] + atomicAdd(&cnt[d], 1);
        ssrc[p] = src[e];
        sew[p]  = ew[e];
    }
}

// ===========================================================================
// FAST PATH: MFMA GEMM with pre-packed operands.
// B tiles: [hl(2)][g(4)][c(128)][8] bf16 = 16 KB (hi+lo split).
// A tiles: hi-only 8 KB where A-lo is dropped/zero; 16 KB full-split tiles
// for GEMM2's agg half (phase 1).
// ===========================================================================

// pack A hi-only (fp32 [M][K] -> bf16, zero-pad rows >= M). grid (NKB, MB).
__global__ __launch_bounds__(512) void pack_a_kernel(
    const float* __restrict__ A, int M, int K,
    int NKB, ushort_t* __restrict__ dst)
{
    const int kb = blockIdx.x, mb = blockIdx.y;
    const int tid = threadIdx.x;
    const int g = tid >> 7, r = tid & 127;
    const int row = mb * 128 + r;

    u16x8 hi;
    if (row < M) {
        const float* src = A + (size_t)row * K + kb * 32 + g * 8;
        float4 v0 = *(const float4*)src;
        float4 v1 = *(const float4*)(src + 4);
        float vals[8] = {v0.x, v0.y, v0.z, v0.w, v1.x, v1.y, v1.z, v1.w};
#pragma unroll
        for (int j = 0; j < 8; ++j) hi[j] = f2bf_rne(vals[j]);
    } else {
#pragma unroll
        for (int j = 0; j < 8; ++j) hi[j] = 0;
    }
    ushort_t* tb = dst + ((size_t)mb * NKB + kb) * 4096;
    *(u16x8*)&tb[g * 1024 + r * 8] = hi;
}

// pack A2 = [agg(fp32) | h(bf16)] logical [M][2048], COMPACT layout:
// per-mb block = 32 full tiles (16KB) + 32 hi-only tiles (8KB) = 768KB.
constexpr size_t kA2Blk = 393216;   // ushorts per mb block
__global__ __launch_bounds__(512) void pack_a2_kernel(
    const float* __restrict__ agg, const ushort_t* __restrict__ hb,
    int M, ushort_t* __restrict__ dst)
{
    const int kb = blockIdx.x, mb = blockIdx.y;   // kb in [0,64)
    const int tid = threadIdx.x;
    const int g = tid >> 7, r = tid & 127;
    const int row = mb * 128 + r;

    if (kb < 32) {
        ushort_t* tb = dst + (size_t)mb * kA2Blk + (size_t)kb * 8192;
        u16x8 hi, lo;
        if (row < M) {
            const float* src = agg + (size_t)row * 1024 + kb * 32 + g * 8;
            float4 v0 = *(const float4*)src;
            float4 v1 = *(const float4*)(src + 4);
            float vals[8] = {v0.x, v0.y, v0.z, v0.w, v1.x, v1.y, v1.z, v1.w};
#pragma unroll
            for (int j = 0; j < 8; ++j) {
                unsigned short h = f2bf_rne(vals[j]);
                hi[j] = h;
                lo[j] = f2bf_rne(vals[j] - bf2f(h));
            }
        } else {
#pragma unroll
            for (int j = 0; j < 8; ++j) { hi[j] = 0; lo[j] = 0; }
        }
        *(u16x8*)&tb[0    + g * 1024 + r * 8] = hi;
        *(u16x8*)&tb[4096 + g * 1024 + r * 8] = lo;
    } else {
        ushort_t* tb = dst + (size_t)mb * kA2Blk + 262144 + (size_t)(kb - 32) * 4096;
        u16x8 hi;
        if (row < M) {
            hi = *(const u16x8*)&hb[(size_t)row * 1024 + (kb - 32) * 32 + g * 8];
        } else {
#pragma unroll
            for (int j = 0; j < 8; ++j) hi[j] = 0;
        }
        *(u16x8*)&tb[g * 1024 + r * 8] = hi;
    }
}

// pack B. mode 0 (col-split): B(k,n) = n<split ? B1[k][n] : B2[k][n-split]
//         mode 1 (row-split): B(k,n) = k<split ? B1[k][n] : B2[(k-split)][n]
__global__ __launch_bounds__(512) void pack_b_kernel(
    const float* __restrict__ B1, const float* __restrict__ B2,
    int N, int split, int mode, ushort_t* __restrict__ dst)
{
    const int kb = blockIdx.x, nb = blockIdx.y;
    const int NKB = gridDim.x;
    const int tid = threadIdx.x;
    const int g = tid >> 7, c = tid & 127;
    const int n = nb * 128 + c;

    u16x8 hi, lo;
#pragma unroll
    for (int j = 0; j < 8; ++j) {
        int k = kb * 32 + g * 8 + j;
        float v;
        if (mode == 0) {
            v = (n < split) ? B1[(size_t)k * split + n]
                            : B2[(size_t)k * (N - split) + (n - split)];
        } else {
            v = (k < split) ? B1[(size_t)k * N + n]
                            : B2[(size_t)(k - split) * N + n];
        }
        unsigned short h = f2bf_rne(v);
        hi[j] = h;
        lo[j] = f2bf_rne(v - bf2f(h));
    }
    ushort_t* tb = dst + ((size_t)nb * NKB + kb) * 8192;
    *(u16x8*)&tb[0    + g * 1024 + c * 8] = hi;
    *(u16x8*)&tb[4096 + g * 1024 + c * 8] = lo;
}

// MFMA GEMM (round-5 structure): phase 1 (kb < nkb_full): bf16x3
// (Ahi*Bhi + Ahi*Blo + Alo*Bhi, 16KB A tiles); phase 2: A-lo dropped
// (Ahi*Bhi + Ahi*Blo, compact 8KB A tiles). nkb_full=0 -> pure 2-product.
// 128x128 tile, BK=32, 4 waves (2x2), 4x4 16x16x32 frags/wave, 32KB LDS.
// Split-output mode (Cbf != null): col<1024 -> bf16 Cbf, col>=1024 -> fp32 C.
// XCD-aware bijective block swizzle (m204) for A-panel L2 locality.
__global__ __launch_bounds__(256) void gemm_mfma(
    const ushort_t* __restrict__ Ap, const ushort_t* __restrict__ Bp,
    const float* __restrict__ bias, int biasN,
    const float* __restrict__ resid, float* __restrict__ C,
    ushort_t* __restrict__ Cbf,
    int M, int N, int NKB, int nkb_full, int do_relu)
{
    __shared__ ushort_t sb[16384];   // 32KB: A tile [0..8191], B tile [8192..]
    const int tid  = threadIdx.x;
    const int wid  = tid >> 6;
    const int lane = tid & 63;
    const int l15 = lane & 15, l4 = lane >> 4;

    const int nwg = gridDim.x * gridDim.y;
    const int lin = blockIdx.y * gridDim.x + blockIdx.x;
    const int q = nwg >> 3, r = nwg & 7;
    const int xcd = lin & 7, pos = lin >> 3;
    const int swz = (xcd < r ? xcd * (q + 1) : r * (q + 1) + (xcd - r) * q) + pos;
    const int mb = swz / gridDim.x, nb = swz % gridDim.x;
    const int wr = wid >> 1, wc = wid & 1;

    f32x4 acc[4][4];
#pragma unroll
    for (int i = 0; i < 4; ++i)
#pragma unroll
        for (int j = 0; j < 4; ++j) acc[i][j] = (f32x4){0.f, 0.f, 0.f, 0.f};

    const size_t a_blk = (size_t)nkb_full * 8192 + (size_t)(NKB - nkb_full) * 4096;
    const char* at = (const char*)(Ap + (size_t)mb * a_blk);
    const char* bt = (const char*)(Bp + (size_t)nb * NKB * 8192);

    // phase 1: full split (3 products per frag)
    for (int kb = 0; kb < nkb_full; ++kb) {
        const char* atk = at + (size_t)kb * 16384;
        const char* btk = bt + (size_t)kb * 16384;
#pragma unroll
        for (int c = 0; c < 4; ++c) {
            __builtin_amdgcn_global_load_lds(
                (gu32*)(atk + c * 4096 + tid * 16),
                (lu32*)&sb[c * 2048 + wid * 512], 16, 0, 0);
            __builtin_amdgcn_global_load_lds(
                (gu32*)(btk + c * 4096 + tid * 16),
                (lu32*)&sb[8192 + c * 2048 + wid * 512], 16, 0, 0);
        }
        __syncthreads();

        bf16x8 af[2][4], bv[2][4];
#pragma unroll
        for (int hl = 0; hl < 2; ++hl)
#pragma unroll
            for (int m = 0; m < 4; ++m)
                af[hl][m] = *(const bf16x8*)&sb[hl * 4096 + l4 * 1024 + (wr * 64 + m * 16 + l15) * 8];
#pragma unroll
        for (int hl = 0; hl < 2; ++hl)
#pragma unroll
            for (int n = 0; n < 4; ++n)
                bv[hl][n] = *(const bf16x8*)&sb[8192 + hl * 4096 + l4 * 1024 + (wc * 64 + n * 16 + l15) * 8];

#pragma unroll
        for (int m = 0; m < 4; ++m)
#pragma unroll
            for (int n = 0; n < 4; ++n) {
                acc[m][n] = __builtin_amdgcn_mfma_f32_16x16x32_bf16(af[0][m], bv[0][n], acc[m][n], 0, 0, 0);
                acc[m][n] = __builtin_amdgcn_mfma_f32_16x16x32_bf16(af[0][m], bv[1][n], acc[m][n], 0, 0, 0);
                acc[m][n] = __builtin_amdgcn_mfma_f32_16x16x32_bf16(af[1][m], bv[0][n], acc[m][n], 0, 0, 0);
            }
        __syncthreads();
    }

    // phase 2: A-lo dropped -> compact 8KB A tiles, 2 products per frag
    for (int kb = nkb_full; kb < NKB; ++kb) {
        const char* atk = at + (size_t)nkb_full * 16384 + (size_t)(kb - nkb_full) * 8192;
        const char* btk = bt + (size_t)kb * 16384;
#pragma unroll
        for (int c = 0; c < 2; ++c) {
            __builtin_amdgcn_global_load_lds(
                (gu32*)(atk + c * 4096 + tid * 16),
                (lu32*)&sb[c * 2048 + wid * 512], 16, 0, 0);
        }
#pragma unroll
        for (int c = 0; c < 4; ++c) {
            __builtin_amdgcn_global_load_lds(
                (gu32*)(btk + c * 4096 + tid * 16),
                (lu32*)&sb[8192 + c * 2048 + wid * 512], 16, 0, 0);
        }
        __syncthreads();

        bf16x8 af0[4], bv[2][4];
#pragma unroll
        for (int m = 0; m < 4; ++m)
            af0[m] = *(const bf16x8*)&sb[l4 * 1024 + (wr * 64 + m * 16 + l15) * 8];
#pragma unroll
        for (int hl = 0; hl < 2; ++hl)
#pragma unroll
            for (int n = 0; n < 4; ++n)
                bv[hl][n] = *(const bf16x8*)&sb[8192 + hl * 4096 + l4 * 1024 + (wc * 64 + n * 16 + l15) * 8];

#pragma unroll
        for (int m = 0; m < 4; ++m)
#pragma unroll
            for (int n = 0; n < 4; ++n) {
                acc[m][n] = __builtin_amdgcn_mfma_f32_16x16x32_bf16(af0[m], bv[0][n], acc[m][n], 0, 0, 0);
                acc[m][n] = __builtin_amdgcn_mfma_f32_16x16x32_bf16(af0[m], bv[1][n], acc[m][n], 0, 0, 0);
            }
        __syncthreads();
    }

    const int row_w = mb * 128 + wr * 64;
    const int col_w = nb * 128 + wc * 64;
    if (Cbf) {
        const bool isxl = (col_w < 1024);   // uniform across the wave's 64-col tile
#pragma unroll
        for (int m = 0; m < 4; ++m) {
#pragma unroll
            for (int n = 0; n < 4; ++n) {
                const int col = col_w + n * 16 + l15;
#pragma unroll
                for (int j = 0; j < 4; ++j) {
                    const int row = row_w + m * 16 + l4 * 4 + j;
                    if (row < M) {
                        float v = acc[m][n][j];
                        if (isxl) {
                            v += bias[col];
                            Cbf[(size_t)row * 1024 + col] = f2bf_rne(v);
                        } else {
                            C[(size_t)row * 1024 + (col - 1024)] = v;
                        }
                    }
                }
            }
        }
    } else {
#pragma unroll
        for (int m = 0; m < 4; ++m) {
#pragma unroll
            for (int n = 0; n < 4; ++n) {
                const int col = col_w + n * 16 + l15;
#pragma unroll
                for (int j = 0; j < 4; ++j) {
                    const int row = row_w + m * 16 + l4 * 4 + j;
                    if (row < M) {
                        float v = acc[m][n][j];
                        if (bias && col < biasN) v += bias[col];
                        if (do_relu) v = fmaxf(v, 0.f);
                        if (resid) v += resid[(size_t)row * N + col];
                        C[(size_t)row * N + col] = v;
                    }
                }
            }
        }
    }
}

// fused GAT, two-pass PER-HEAD softmax (H=4, 256 cols each).
// Pass 1: wave w handles edges w, w+4, ...; each lane computes 4-col partials
// of ALL FOUR head logits (lane's cols i*256+lane*4 lie in head i); 4 separate
// 64-lane reductions -> slog[h][e]. Per-head chunk max: wave h reduces head h.
// Pass 2: thread owns cols tid*4 (head = tid>>6 = wave); pure gather+FMA with
// per-head weights; D accumulated per thread (per-head). Chunked at 512.
__global__ __launch_bounds__(256) void gat2_kernel(
    const ushort_t* __restrict__ xlb, const float* __restrict__ xrb,
    const int* __restrict__ ssrc, const float* __restrict__ sew,
    const int* __restrict__ offsets, const float* __restrict__ loopat,
    const float* __restrict__ We, const float* __restrict__ att,
    const float* __restrict__ bgat, ushort_t* __restrict__ hout)
{
    const int n = blockIdx.x;
    const int tid = threadIdx.x;
    const int wave = tid >> 6, lane = tid & 63;
    __shared__ float slog[4][512];
    __shared__ float sNewM[4];

    // pass-1 lane constants: head i, cols c = i*256 + lane*4
    float4 xr1[4], We1[4], at1[4];
#pragma unroll
    for (int i = 0; i < 4; ++i) {
        const int c = i * 256 + lane * 4;
        xr1[i] = *(const float4*)&xrb[(size_t)n * 1024 + c];
        We1[i] = *(const float4*)&We[c];
        at1[i] = *(const float4*)&att[c];
    }

    const int beg = offsets[n], end = offsets[n + 1];   // self-loop at e==end
    const int base = tid * 4;

    float Mloc = -INFINITY, D = 0.f;
    float4 acc = make_float4(0.f, 0.f, 0.f, 0.f);

    for (int cbeg = beg; cbeg <= end; cbeg += 512) {
        const int cend = min(cbeg + 512, end + 1);
        const int cn = cend - cbeg;

        // pass 1: per-wave edges, per-head logits
        for (int e = cbeg + wave; e < cend; e += 4) {
            int s; float w;
            if (e < end) { s = ssrc[e]; w = sew[e]; }
            else         { s = n;       w = loopat[n]; }
            const ushort_t* xrow = &xlb[(size_t)s * 1024];
            float p[4];
#pragma unroll
            for (int i = 0; i < 4; ++i) {
                const int c = i * 256 + lane * 4;
                const u16x4 xh = *(const u16x4*)&xrow[c];
                float m0 = bf2f(xh[0]) + xr1[i].x + w * We1[i].x;
                float m1 = bf2f(xh[1]) + xr1[i].y + w * We1[i].y;
                float m2 = bf2f(xh[2]) + xr1[i].z + w * We1[i].z;
                float m3 = bf2f(xh[3]) + xr1[i].w + w * We1[i].w;
                m0 = (m0 >= 0.f) ? m0 : 0.2f * m0;
                m1 = (m1 >= 0.f) ? m1 : 0.2f * m1;
                m2 = (m2 >= 0.f) ? m2 : 0.2f * m2;
                m3 = (m3 >= 0.f) ? m3 : 0.2f * m3;
                p[i] = m0 * at1[i].x + m1 * at1[i].y + m2 * at1[i].z + m3 * at1[i].w;
            }
#pragma unroll
            for (int i = 0; i < 4; ++i)
#pragma unroll
                for (int o = 32; o >= 1; o >>= 1) p[i] += __shfl_xor(p[i], o, 64);
            if (lane == 0) {
                const int idx = e - cbeg;
                slog[0][idx] = p[0]; slog[1][idx] = p[1];
                slog[2][idx] = p[2]; slog[3][idx] = p[3];
            }
        }
        __syncthreads();

        // per-head chunk max: wave h reduces head h (combined with running max)
        {
            float m = Mloc;
            for (int i = lane; i < cn; i += 64) m = fmaxf(m, slog[wave][i]);
#pragma unroll
            for (int o = 32; o >= 1; o >>= 1) m = fmaxf(m, __shfl_xor(m, o, 64));
            if (lane == 0) sNewM[wave] = m;
        }
        __syncthreads();

        // logits -> weights in LDS (all heads), and rescale running sums
        for (int f = tid; f < 2048; f += 256) {
            const int h = f >> 9, i = f & 511;
            if (i < cn) slog[h][i] = __expf(slog[h][i] - sNewM[h]);
        }
        const float newM = sNewM[wave];
        const float scale = __expf(Mloc - newM);   // first chunk: exp(-inf)=0
        D *= scale;
        acc.x *= scale; acc.y *= scale; acc.z *= scale; acc.w *= scale;
        __syncthreads();

        // pass 2: weighted gather (thread's head = wave), fully pipelineable
        for (int e = cbeg; e < cend; ++e) {
            const int s = (e < end) ? ssrc[e] : n;
            const float wx = slog[wave][e - cbeg];   // LDS broadcast per wave
            const u16x4 xh = *(const u16x4*)&xlb[(size_t)s * 1024 + base];
            acc.x += wx * bf2f(xh[0]);
            acc.y += wx * bf2f(xh[1]);
            acc.z += wx * bf2f(xh[2]);
            acc.w += wx * bf2f(xh[3]);
            D += wx;
        }
        Mloc = newM;
        __syncthreads();   // slog/sNewM reused by next chunk
    }

    const float inv = 1.0f / (D + 1e-16f);
    float g0 = acc.x * inv + bgat[base + 0];
    float g1 = acc.y * inv + bgat[base + 1];
    float g2 = acc.z * inv + bgat[base + 2];
    float g3 = acc.w * inv + bgat[base + 3];
    u16x4 hv;
    hv[0] = f2bf_rne((g0 > 0.f) ? g0 : expm1f(g0));
    hv[1] = f2bf_rne((g1 > 0.f) ? g1 : expm1f(g1));
    hv[2] = f2bf_rne((g2 > 0.f) ? g2 : expm1f(g2));
    hv[3] = f2bf_rne((g3 > 0.f) ? g3 : expm1f(g3));
    *(u16x4*)&hout[(size_t)n * 1024 + base] = hv;
}

// agg: mean of bf16 h[src] rows -> fp32 agg
__global__ __launch_bounds__(256) void agg2_kernel(
    const ushort_t* __restrict__ hb, const int* __restrict__ ssrc,
    const int* __restrict__ offsets, float* __restrict__ aggout)
{
    const int n = blockIdx.x;
    const int base = threadIdx.x * 4;
    float4 a = make_float4(0.f, 0.f, 0.f, 0.f);
    const int beg = offsets[n], end = offsets[n + 1];
    for (int e = beg; e < end; ++e) {
        const u16x4 hv = *(const u16x4*)&hb[(size_t)ssrc[e] * 1024 + base];
        a.x += bf2f(hv[0]); a.y += bf2f(hv[1]);
        a.z += bf2f(hv[2]); a.w += bf2f(hv[3]);
    }
    const float inv = 1.0f / fmaxf((float)(end - beg), 1.0f);
    a.x *= inv; a.y *= inv; a.z *= inv; a.w *= inv;
    *(float4*)&aggout[(size_t)n * 1024 + base] = a;
}

// ---------------------------------------------------------------------------
// LayerNorm over last dim (1280), in-place. 320 threads x float4 per row.
// ---------------------------------------------------------------------------
__global__ __launch_bounds__(320) void ln_kernel(
    float* __restrict__ z, const float* __restrict__ gamma,
    const float* __restrict__ beta)
{
    const int r = blockIdx.x;
    const int t = threadIdx.x;
    const int wave = t >> 6, lane = t & 63;
    __shared__ float red[5];

    float4 v = *(const float4*)&z[(size_t)r * kESM + t * 4];
    float s = v.x + v.y + v.z + v.w;
#pragma unroll
    for (int o = 32; o >= 1; o >>= 1) s += __shfl_xor(s, o, 64);
    if (lane == 0) red[wave] = s;
    __syncthreads();
    s = red[0] + red[1] + red[2] + red[3] + red[4];
    const float mu = s * (1.0f / (float)kESM);

    float dx = v.x - mu, dy = v.y - mu, dz = v.z - mu, dw = v.w - mu;
    float q = dx * dx + dy * dy + dz * dz + dw * dw;
#pragma unroll
    for (int o = 32; o >= 1; o >>= 1) q += __shfl_xor(q, o, 64);
    __syncthreads();
    if (lane == 0) red[wave] = q;
    __syncthreads();
    q = red[0] + red[1] + red[2] + red[3] + red[4];
    const float rstd = rsqrtf(q * (1.0f / (float)kESM) + 1e-5f);

    const float4 g4 = *(const float4*)&gamma[t * 4];
    const float4 b4 = *(const float4*)&beta[t * 4];
    float4 o;
    o.x = dx * rstd * g4.x + b4.x;
    o.y = dy * rstd * g4.y + b4.y;
    o.z = dz * rstd * g4.z + b4.z;
    o.w = dw * rstd * g4.w + b4.w;
    *(float4*)&z[(size_t)r * kESM + t * 4] = o;
}

// ===========================================================================
// FALLBACK PATH (round-2, known-pass): fp32 vector GEMM + fp32 gat/agg
// ===========================================================================
#define BM 128
#define BN 128
#define BK 16

__global__ __launch_bounds__(256) void gemm_kernel(
    const float* __restrict__ A,  const float* __restrict__ B,
    const float* __restrict__ A2, const float* __restrict__ B2,
    const float* __restrict__ bias, const float* __restrict__ resid,
    float* __restrict__ C, int M, int N, int K, int do_relu)
{
    __shared__ float As[BK][BM];
    __shared__ float Bs[BK][BN];

    const int tid = threadIdx.x;
    const int bm = blockIdx.y, bn = blockIdx.x;
    const int row0 = bm * BM, col0 = bn * BN;
    const int tx = tid & 15, ty = tid >> 4;

    float acc[8][8];
#pragma unroll
    for (int i = 0; i < 8; ++i)
#pragma unroll
        for (int j = 0; j < 8; ++j) acc[i][j] = 0.0f;

    const int arow  = tid >> 1;
    const int akoff = (tid & 1) * 8;
    const int bkr   = tid >> 4;
    const int bcol  = (tid & 15) * 8;

    for (int pair = 0; pair < 2; ++pair) {
        const float* Ap = pair ? A2 : A;
        const float* Bp = pair ? B2 : B;
        if (!Ap) break;
        for (int k0 = 0; k0 < K; k0 += BK) {
            float4 a0 = make_float4(0.f, 0.f, 0.f, 0.f);
            float4 a1 = a0;
            int gr = row0 + arow;
            if (gr < M) {
                const float* aptr = Ap + (size_t)gr * K + k0 + akoff;
                a0 = *(const float4*)aptr;
                a1 = *(const float4*)(aptr + 4);
            }
            const float* bptr = Bp + (size_t)(k0 + bkr) * N + col0 + bcol;
            float4 b0 = *(const float4*)bptr;
            float4 b1 = *(const float4*)(bptr + 4);

            __syncthreads();
            As[akoff + 0][arow] = a0.x;
            As[akoff + 1][arow] = a0.y;
            As[akoff + 2][arow] = a0.z;
            As[akoff + 3][arow] = a0.w;
            As[akoff + 4][arow] = a1.x;
            As[akoff + 5][arow] = a1.y;
            As[akoff + 6][arow] = a1.z;
            As[akoff + 7][arow] = a1.w;
            *(float4*)&Bs[bkr][bcol]     = b0;
            *(float4*)&Bs[bkr][bcol + 4] = b1;
            __syncthreads();

#pragma unroll
            for (int kk = 0; kk < BK; ++kk) {
                float4 a0r = *(const float4*)&As[kk][ty * 8];
                float4 a1r = *(const float4*)&As[kk][ty * 8 + 4];
                float4 b0r = *(const float4*)&Bs[kk][tx * 4];
                float4 b1r = *(const float4*)&Bs[kk][64 + tx * 4];
                float ar[8] = {a0r.x, a0r.y, a0r.z, a0r.w, a1r.x, a1r.y, a1r.z, a1r.w};
                float br[8] = {b0r.x, b0r.y, b0r.z, b0r.w, b1r.x, b1r.y, b1r.z, b1r.w};
#pragma unroll
                for (int i = 0; i < 8; ++i)
#pragma unroll
                    for (int j = 0; j < 8; ++j)
                        acc[i][j] = fmaf(ar[i], br[j], acc[i][j]);
            }
        }
    }

#pragma unroll
    for (int i = 0; i < 8; ++i) {
        int gr = row0 + ty * 8 + i;
        if (gr >= M) break;
#pragma unroll
        for (int half = 0; half < 2; ++half) {
            int gc = col0 + half * 64 + tx * 4;
            float4 out;
            float* o = &out.x;
            const float* rrow = resid ? (resid + (size_t)gr * N + gc) : nullptr;
#pragma unroll
            for (int j = 0; j < 4; ++j) {
                float v = acc[i][half * 4 + j];
                if (bias) v += bias[gc + j];
                if (do_relu) v = fmaxf(v, 0.0f);
                if (rrow) v += rrow[j];
                o[j] = v;
            }
            *(float4*)&C[(size_t)gr * N + gc] = out;
        }
    }
}

__global__ __launch_bounds__(256) void gat_kernel(
    const float* __restrict__ xl, const float* __restrict__ xr,
    const int* __restrict__ ssrc, const float* __restrict__ sew,
    const int* __restrict__ offsets, const float* __restrict__ loopat,
    const float* __restrict__ We, const float* __restrict__ att,
    const float* __restrict__ bgat, float* __restrict__ hout)
{
    const int n = blockIdx.x;
    const int base = threadIdx.x * 4;

    const float4 xr4 = *(const float4*)&xr[(size_t)n * kHC + base];
    const float4 We4 = *(const float4*)&We[base];
    const float4 at4 = *(const float4*)&att[base];

    float M = -INFINITY, D = 0.f;
    float4 acc = make_float4(0.f, 0.f, 0.f, 0.f);

    const int beg = offsets[n], end = offsets[n + 1];
    for (int e = beg; e <= end; ++e) {
        int s; float w;
        if (e < end) { s = ssrc[e]; w = sew[e]; }
        else         { s = n;       w = loopat[n]; }

        const float4 xls = *(const float4*)&xl[(size_t)s * kHC + base];
        float m0 = xls.x + xr4.x + w * We4.x;
        float m1 = xls.y + xr4.y + w * We4.y;
        float m2 = xls.z + xr4.z + w * We4.z;
        float m3 = xls.w + xr4.w + w * We4.w;
        m0 = (m0 >= 0.f) ? m0 : 0.2f * m0;
        m1 = (m1 >= 0.f) ? m1 : 0.2f * m1;
        m2 = (m2 >= 0.f) ? m2 : 0.2f * m2;
        m3 = (m3 >= 0.f) ? m3 : 0.2f * m3;
        float p = m0 * at4.x + m1 * at4.y + m2 * at4.z + m3 * at4.w;
#pragma unroll
        for (int o = 32; o >= 1; o >>= 1) p += __shfl_xor(p, o, 64);

        float newM  = fmaxf(M, p);
        float scale = __expf(M - newM);
        float wexp  = __expf(p - newM);
        D     = D * scale + wexp;
        acc.x = acc.x * scale + wexp * xls.x;
        acc.y = acc.y * scale + wexp * xls.y;
        acc.z = acc.z * scale + wexp * xls.z;
        acc.w = acc.w * scale + wexp * xls.w;
        M = newM;
    }

    const float inv = 1.0f / (D + 1e-16f);
    float g0 = acc.x * inv + bgat[base + 0];
    float g1 = acc.y * inv + bgat[base + 1];
    float g2 = acc.z * inv + bgat[base + 2];
    float g3 = acc.w * inv + bgat[base + 3];
    float4 hv;
    hv.x = (g0 > 0.f) ? g0 : expm1f(g0);
    hv.y = (g1 > 0.f) ? g1 : expm1f(g1);
    hv.z = (g2 > 0.f) ? g2 : expm1f(g2);
    hv.w = (g3 > 0.f) ? g3 : expm1f(g3);
    *(float4*)&hout[(size_t)n * kHC + base] = hv;
}

__global__ __launch_bounds__(256) void agg_kernel(
    const float* __restrict__ h, const int* __restrict__ ssrc,
    const int* __restrict__ offsets, float* __restrict__ aggout)
{
    const int n = blockIdx.x;
    const int base = threadIdx.x * 4;
    float4 a = make_float4(0.f, 0.f, 0.f, 0.f);
    const int beg = offsets[n], end = offsets[n + 1];
    for (int e = beg; e < end; ++e) {
        const float4 hv = *(const float4*)&h[(size_t)ssrc[e] * kHC + base];
        a.x += hv.x; a.y += hv.y; a.z += hv.z; a.w += hv.w;
    }
    const float inv = 1.0f / fmaxf((float)(end - beg), 1.0f);
    a.x *= inv; a.y *= inv; a.z *= inv; a.w *= inv;
    *(float4*)&aggout[(size_t)n * kHC + base] = a;
}

// Old 256-thread scan kept for fallback path
__global__ __launch_bounds__(256) void scan_kernel_fb(
    const int* __restrict__ deg, float* __restrict__ loopat,
    int* __restrict__ offsets)
{
    __shared__ int s[256];
    int tid = threadIdx.x;
    int base = 0;
    if (tid == 0) offsets[0] = 0;
    for (int t0 = 0; t0 < kN; t0 += 256) {
        int i = t0 + tid;
        int d = (i < kN) ? deg[i] : 0;
        if (i < kN) {
            float w = loopat[i];
            loopat[i] = w / fmaxf((float)d, 1.0f);
        }
        s[tid] = d;
        int v = d;
        for (int off = 1; off < 256; off <<= 1) {
            __syncthreads();
            int add = (tid >= off) ? s[tid - off] : 0;
            __syncthreads();
            v += add;
            s[tid] = v;
        }
        __syncthreads();
        if (i < kN) offsets[i + 1] = base + v;
        base += s[255];
        __syncthreads();
    }
}

// ---------------------------------------------------------------------------
extern "C" void kernel_launch(void* const* d_in, const int* in_sizes, int n_in,
                              void* d_out, int out_size, void* d_ws, size_t ws_size,
                              hipStream_t stream)
{
    const float* x     = (const float*)d_in[0];
    const int*   ei    = (const int*)  d_in[1];
    const float* ew    = (const float*)d_in[2];
    const float* Wl    = (const float*)d_in[3];
    const float* bl    = (const float*)d_in[4];
    const float* Wr    = (const float*)d_in[5];
    const float* We    = (const float*)d_in[6];
    const float* att   = (const float*)d_in[7];
    const float* bgat  = (const float*)d_in[8];
    const float* Wsl   = (const float*)d_in[9];
    const float* bsl   = (const float*)d_in[10];
    const float* Wsr   = (const float*)d_in[11];
    const float* gamma = (const float*)d_in[12];
    const float* beta  = (const float*)d_in[13];
    const int* src = ei;
    const int* dst = ei + kE;
    char* ws = (char*)d_ws;

    // fast-path layout (bytes), NO overlaps among concurrently-live buffers:
    //   [xlb 41M)[xrb 82M)[hbuf 41M)[b2p 10.5M)[apack 123.5M)[smalls]
    // aliases (strictly dead-before-reuse):
    //   xpack (51.4M) + b1p (10.5M) inside apack region (dead after GEMM1,
    //     apack written later by pack_a2);
    //   aggb (82M) at ws+0 over xlb+xrb (both dead after gat2).
    const size_t SZ_XLB  = (size_t)kN * 1024 * 2;            //  40,960,000
    const size_t SZ_XRB  = (size_t)kN * 1024 * 4;            //  81,920,000
    const size_t SZ_HBF  = (size_t)kN * 1024 * 2;            //  40,960,000
    const size_t SZ_B2   = (size_t)10 * 64 * 16384;          //  10,485,760
    const size_t SZ_APK  = (size_t)157 * kA2Blk * 2;         // 123,469,824
    const size_t SZ_XPK  = (size_t)157 * 40 * 8192;          //  51,445,760
    const size_t OFF_XRB = SZ_XLB;                           //  40,960,000
    const size_t OFF_HBF = OFF_XRB + SZ_XRB;                 // 122,880,000
    const size_t OFF_B2  = OFF_HBF + SZ_HBF;                 // 163,840,000
    const size_t OFF_APK = OFF_B2 + SZ_B2;                   // 174,325,760
    const size_t OFF_XPK = OFF_APK;                          // alias (dead-early)
    const size_t OFF_B1  = OFF_APK + SZ_XPK;                 // 225,771,520 (alias)
    size_t off = OFF_APK + SZ_APK;                           // 297,795,584
    auto salloc = [&](size_t bytes) -> void* {
        void* p = ws + off;
        off = (off + bytes + 255) & ~(size_t)255;
        return p;
    };
    int*   deg    = (int*)  salloc((size_t)kN * 4);
    int*   cnt    = (int*)  salloc((size_t)kN * 4);
    int*   offs   = (int*)  salloc((size_t)(kN + 1) * 4);
    float* loopat = (float*)salloc((size_t)kN * 4);
    int*   ssrc   = (int*)  salloc((size_t)kE * 4);
    float* sew    = (float*)salloc((size_t)kE * 4);
    const size_t FAST_TOTAL = off;   // ~299 MB (ws >= 331 MB proven in rounds 3-5)

    if (ws_size >= FAST_TOTAL) {
        // ------------------ FAST PATH ------------------
        ushort_t* xlb   = (ushort_t*)(ws);
        float*    xrb   = (float*)   (ws + OFF_XRB);
        ushort_t* hbuf  = (ushort_t*)(ws + OFF_HBF);
        ushort_t* b2p   = (ushort_t*)(ws + OFF_B2);
        ushort_t* apack = (ushort_t*)(ws + OFF_APK);
        ushort_t* xpack = (ushort_t*)(ws + OFF_XPK);
        ushort_t* b1p   = (ushort_t*)(ws + OFF_B1);
        float*    aggb  = (float*)   (ws);   // over dead xlb+xrb after gat2

        hipMemsetAsync(deg,    0, (size_t)kN * 4, stream);
        hipMemsetAsync(cnt,    0, (size_t)kN * 4, stream);
        hipMemsetAsync(loopat, 0, (size_t)kN * 4, stream);

        deg_kernel <<<(kE + 255) / 256, 256, 0, stream>>>(dst, ew, deg, loopat);
        scan_kernel<<<1, 1024, 0, stream>>>(deg, loopat, offs);
        sort_kernel<<<(kE + 255) / 256, 256, 0, stream>>>(src, dst, ew, offs, cnt, ssrc, sew);

        pack_a_kernel<<<dim3(40, 157), 512, 0, stream>>>(x, kN, kESM, 40, xpack);
        pack_b_kernel<<<dim3(40, 16), 512, 0, stream>>>(Wl, Wr, 2048, 1024, 0, b1p);
        pack_b_kernel<<<dim3(64, 10), 512, 0, stream>>>(Wsl, Wsr, 1280, 1024, 1, b2p);

        // GEMM1: 2-product (A hi-only, nkb_full=0); split output xl->bf16, xr->fp32
        gemm_mfma<<<dim3(16, 157), 256, 0, stream>>>(xpack, b1p, bl, 1024,
                                                     nullptr, xrb, xlb,
                                                     kN, 2048, 40, 0, 0);

        gat2_kernel<<<kN, 256, 0, stream>>>(xlb, xrb, ssrc, sew, offs, loopat,
                                            We, att, bgat, hbuf);
        agg2_kernel<<<kN, 256, 0, stream>>>(hbuf, ssrc, offs, aggb);

        pack_a2_kernel<<<dim3(64, 157), 512, 0, stream>>>(aggb, hbuf, kN, apack);

        // GEMM2: agg half full-split (32 tiles), h half 2-product
        gemm_mfma<<<dim3(10, 157), 256, 0, stream>>>(apack, b2p, bsl, 1280,
                                                     x, (float*)d_out, nullptr,
                                                     kN, 1280, 64, 32, 1);

        ln_kernel<<<kN, 320, 0, stream>>>((float*)d_out, gamma, beta);
    } else {
        // ------------------ FALLBACK (round-2) ------------------
        size_t foff = 0;
        auto falloc = [&](size_t bytes) -> void* {
            void* p = ws + foff;
            foff = (foff + bytes + 255) & ~(size_t)255;
            return p;
        };
        int*   fdeg    = (int*)  falloc((size_t)kN * 4);
        int*   fcnt    = (int*)  falloc((size_t)kN * 4);
        int*   foffs   = (int*)  falloc((size_t)(kN + 1) * 4);
        float* floopat = (float*)falloc((size_t)kN * 4);
        int*   fssrc   = (int*)  falloc((size_t)kE * 4);
        float* fsew    = (float*)falloc((size_t)kE * 4);
        float* bufA    = (float*)falloc((size_t)kN * kHC * 4);
        float* bufB    = (float*)falloc((size_t)kN * kHC * 4);

        hipMemsetAsync(fdeg,    0, (size_t)kN * 4, stream);
        hipMemsetAsync(fcnt,    0, (size_t)kN * 4, stream);
        hipMemsetAsync(floopat, 0, (size_t)kN * 4, stream);

        deg_kernel <<<(kE + 255) / 256, 256, 0, stream>>>(dst, ew, fdeg, floopat);
        scan_kernel_fb<<<1, 256, 0, stream>>>(fdeg, floopat, foffs);
        sort_kernel<<<(kE + 255) / 256, 256, 0, stream>>>(src, dst, ew, foffs, fcnt, fssrc, fsew);

        dim3 g1(kHC / BN, (kN + BM - 1) / BM);
        gemm_kernel<<<g1, 256, 0, stream>>>(x, Wl, nullptr, nullptr, bl, nullptr,
                                            bufA, kN, kHC, kESM, 0);
        gemm_kernel<<<g1, 256, 0, stream>>>(x, Wr, nullptr, nullptr, nullptr, nullptr,
                                            bufB, kN, kHC, kESM, 0);

        gat_kernel<<<kN, 256, 0, stream>>>(bufA, bufB, fssrc, fsew, foffs, floopat,
                                           We, att, bgat, bufB);
        agg_kernel<<<kN, 256, 0, stream>>>(bufB, fssrc, foffs, bufA);

        dim3 g2(kESM / BN, (kN + BM - 1) / BM);
        gemm_kernel<<<g2, 256, 0, stream>>>(bufA, Wsl, bufB, Wsr, bsl, x,
                                            (float*)d_out, kN, kESM, kHC, 1);

        ln_kernel<<<kN, 320, 0, stream>>>((float*)d_out, gamma, beta);
    }
}